// Round 13
// baseline (465.349 us; speedup 1.0000x reference)
//
#include <hip/hip_runtime.h>
#include <hip/hip_bf16.h>
#include <math.h>

#define NT 512

typedef __attribute__((ext_vector_type(8))) short short8v;
typedef __attribute__((ext_vector_type(4))) short short4v;
typedef __attribute__((ext_vector_type(4))) float f32x4;
typedef __attribute__((ext_vector_type(2))) unsigned uint2v;
typedef __attribute__((ext_vector_type(4))) unsigned uint4v;

__device__ __forceinline__ unsigned short f2bf(float x) {   // prep kernel only
    unsigned u = __float_as_uint(x);
    unsigned r = ((u >> 16) & 1u) + 0x7FFFu;
    return (unsigned short)((u + r) >> 16);
}
__device__ __forceinline__ unsigned pk2(float a, float b) {
    __hip_bfloat162 h = __float22bfloat162_rn(make_float2(a, b));
    unsigned r;
    __builtin_memcpy(&r, &h, sizeof(r));
    return r;
}
__device__ __forceinline__ short bf1(float a) {
    __hip_bfloat16 h = __float2bfloat16(a);
    short r;
    __builtin_memcpy(&r, &h, sizeof(r));
    return r;
}
__device__ __forceinline__ float exp2fast(float x) {
#if __has_builtin(__builtin_amdgcn_exp2f)
    return __builtin_amdgcn_exp2f(x);
#else
    return exp2f(x);
#endif
}
__device__ __forceinline__ float rcpfast(float x) {
#if __has_builtin(__builtin_amdgcn_rcpf)
    return __builtin_amdgcn_rcpf(x);
#else
    return 1.0f / x;
#endif
}
// tanh-form gelu via exp2 + rcp (|err| vs erf-gelu ~3e-3, inside tolerance)
__device__ __forceinline__ float gelu_f(float x) {
    float x3 = x * x * x;
    float e = exp2fast(-2.3022079f * x - 0.1029432f * x3);
    return x * rcpfast(1.0f + e);
}
__device__ __forceinline__ f32x4 mfma32(short8v a, short8v b, f32x4 c) {
    return __builtin_amdgcn_mfma_f32_16x16x32_bf16(a, b, c, 0, 0, 0);
}
__device__ __forceinline__ f32x4 mfma16(short4v a, short4v b, f32x4 c) {
    return __builtin_amdgcn_mfma_f32_16x16x16bf16_1k(a, b, c, 0, 0, 0);
}

template<int M>
__device__ __forceinline__ void stats_tree(const f32x4* v, float& s1o, float& s2o) {
    float a[M], b[M];
    #pragma unroll
    for (int i = 0; i < M; ++i) {
        a[i] = (v[i][0] + v[i][1]) + (v[i][2] + v[i][3]);
        float q0 = v[i][0] * v[i][0], q1 = v[i][1] * v[i][1];
        float q2 = v[i][2] * v[i][2], q3 = v[i][3] * v[i][3];
        b[i] = (q0 + q1) + (q2 + q3);
    }
    #pragma unroll
    for (int s = 1; s < M; s *= 2)
        #pragma unroll
        for (int i = 0; i + s < M; i += 2 * s) { a[i] += a[i + s]; b[i] += b[i + s]; }
    s1o = a[0]; s2o = b[0];
}

// ws layout (bf16 shorts): wqkvT[L][192][64] @0 ; woT[L][64][64] @49152 ;
//                          w1T[L][16][64] @65536 (rows j>=8 zero) ; w2T[L][64][8] @69632
#define WS_WO 49152
#define WS_W1 65536
#define WS_W2 69632
#define WS_TOT 71680

__global__ __launch_bounds__(256) void prep_kernel(
    const float* __restrict__ w_qkv, const float* __restrict__ w_o,
    const float* __restrict__ w1, const float* __restrict__ w2,
    short* __restrict__ ws)
{
    int idx = blockIdx.x * 256 + threadIdx.x;
    if (idx < WS_WO) {
        int l = idx / 12288, r = idx % 12288, c = r >> 6, d = r & 63;
        ws[idx] = (short)f2bf(w_qkv[l * 12288 + d * 192 + c]);
    } else if (idx < WS_W1) {
        int k = idx - WS_WO; int l = k / 4096, r = k % 4096, c = r >> 6, d = r & 63;
        ws[idx] = (short)f2bf(w_o[l * 4096 + d * 64 + c]);
    } else if (idx < WS_W2) {
        int k = idx - WS_W1; int l = k / 1024, r = k % 1024, j = r >> 6, d = r & 63;
        ws[idx] = (j < 8) ? (short)f2bf(w1[l * 512 + d * 8 + j]) : (short)0;
    } else if (idx < WS_TOT) {
        int k = idx - WS_W2; int l = k / 512, r = k % 512, c = r >> 3, j = r & 7;
        ws[idx] = (short)f2bf(w2[l * 512 + j * 64 + c]);
    }
}

// LDS (51.2 KB -> 3 blocks/CU): xs fp32 [81][68] (full 9x9 grid, ring-indexed);
// ybuf bf16 [96][72] = LN1 input (written by prev phase D); abuf bf16 [96][72]
// = attention output (written in fused QKV+attn phase); hb bf16 [96][8] MLP hidden.
// Fused QKV+attention: wave h owns head h end-to-end; q/k/v never touch LDS.
template<int N, int P, int L, bool FIRST, bool LAST>
__device__ __forceinline__ void layer_fn(
    float* __restrict__ xs, short* __restrict__ ybuf, short* __restrict__ abuf,
    short* __restrict__ hb, const short* __restrict__ ws,
    const float* __restrict__ b_qkv, const float* __restrict__ b_o,
    const float* __restrict__ ln1_g, const float* __restrict__ ln1_b,
    const float* __restrict__ ln2_g, const float* __restrict__ ln2_b,
    const float* __restrict__ b1,    const float* __restrict__ b2,
    float* __restrict__ out, int b, int t)
{
    constexpr int Mt = (N + 15) / 16;
    constexpr float SCL2E = 0.51010905835f;   // (HEAD_DIM/HEADS)^-0.5 * log2(e)
    const int wv = t >> 6, l = t & 63, lr = l & 15, lq = l >> 4;
    short8v zero8 = {};
    f32x4 zero4 = {0.f, 0.f, 0.f, 0.f};

    // ---- phase A (first layer only): LN1 -> ybuf. 4 lanes per token ----
    if (FIRST) {
        if (t < 64 * Mt) {
            const int token = t >> 2, part = t & 3, d0 = part * 16;
            short* yrow = ybuf + token * 72 + d0;
            if (token < N) {
                const int row = (token / P + L) * 9 + token % P + L;
                const float* xr = xs + row * 68 + d0;
                f32x4 v[4];
                #pragma unroll
                for (int k = 0; k < 4; ++k) v[k] = *(const f32x4*)(xr + 4 * k);
                float s1, s2;
                stats_tree<4>(v, s1, s2);
                s1 += __shfl_xor(s1, 1); s2 += __shfl_xor(s2, 1);
                s1 += __shfl_xor(s1, 2); s2 += __shfl_xor(s2, 2);
                const float m = s1 * 0.015625f;
                const float r = rsqrtf(s2 * 0.015625f - m * m + 1e-5f);
                uint4v w0, w1v;
                #pragma unroll
                for (int k = 0; k < 4; ++k) {
                    f32x4 g  = *(const f32x4*)&ln1_g[L * 64 + d0 + 4 * k];
                    f32x4 bb = *(const f32x4*)&ln1_b[L * 64 + d0 + 4 * k];
                    unsigned p0 = pk2((v[k][0]-m)*r*g[0]+bb[0], (v[k][1]-m)*r*g[1]+bb[1]);
                    unsigned p1 = pk2((v[k][2]-m)*r*g[2]+bb[2], (v[k][3]-m)*r*g[3]+bb[3]);
                    if (k == 0) { w0.x = p0; w0.y = p1; }
                    else if (k == 1) { w0.z = p0; w0.w = p1; }
                    else if (k == 2) { w1v.x = p0; w1v.y = p1; }
                    else { w1v.z = p0; w1v.w = p1; }
                }
                *(uint4v*)yrow = w0;
                *(uint4v*)(yrow + 8) = w1v;
            } else {
                uint4v z = {};
                *(uint4v*)yrow = z;
                *(uint4v*)(yrow + 8) = z;
            }
        }
        __syncthreads();
    }

    // ---- fused QKV + attention: wave = head h. q/k/v in registers. ----
    {
        const int h = wv, a = h & 1, ct = h >> 1;
        // gather source lane for q/k redistribution (swapped-GEMM D -> _1k fragment)
        const int srcl = lr + 32 * a + (l & 16);
        const short* wqL = ws + L * 12288;

        // V pass: unswapped GEMM -> D fragment == PV A-operand fragment directly
        short4v vf[Mt];
        {
            const short* wvr = &wqL[(128 + 16 * ct + lr) * 64 + lq * 8];
            short8v wv0 = *(const short8v*)wvr, wv1 = *(const short8v*)(wvr + 32);
            const float vb = b_qkv[L * 192 + 128 + 16 * ct + lr];
            #pragma unroll
            for (int mt = 0; mt < Mt; ++mt) {
                const short* yr = &ybuf[(16 * mt + lr) * 72 + lq * 8];
                short8v y0 = *(const short8v*)yr, y1 = *(const short8v*)(yr + 32);
                f32x4 acc = mfma32(y0, wv0, zero4);
                acc = mfma32(y1, wv1, acc);
                uint2v u;
                u.x = pk2(acc[0] + vb, acc[1] + vb);
                u.y = pk2(acc[2] + vb, acc[3] + vb);
                vf[mt] = __builtin_bit_cast(short4v, u);
            }
        }
        // K pass: swapped GEMM, redistribute (2 shfl) -> scores A fragment
        uint2v kf[Mt];
        {
            const short* wkr = &wqL[(64 + 16 * ct + lr) * 64 + lq * 8];
            short8v wk0 = *(const short8v*)wkr, wk1 = *(const short8v*)(wkr + 32);
            f32x4 kb = *(const f32x4*)&b_qkv[L * 192 + 64 + 16 * ct + lq * 4];
            #pragma unroll
            for (int mt = 0; mt < Mt; ++mt) {
                const short* yr = &ybuf[(16 * mt + lr) * 72 + lq * 8];
                short8v y0 = *(const short8v*)yr, y1 = *(const short8v*)(yr + 32);
                f32x4 acc = mfma32(wk0, y0, zero4);
                acc = mfma32(wk1, y1, acc);
                unsigned ka = pk2(acc[0] + kb[0], acc[1] + kb[1]);
                unsigned kc = pk2(acc[2] + kb[2], acc[3] + kb[3]);
                unsigned u0 = (unsigned)__shfl((int)ka, srcl);
                unsigned u1 = (unsigned)__shfl((int)kc, srcl);
                uint2v kv; kv.x = (l < 32) ? u0 : 0u; kv.y = (l < 32) ? u1 : 0u;
                kf[mt] = kv;
            }
        }
        // Q pass: swapped GEMM with softmax scale folded, same redistribution
        uint2v qf[Mt];
        {
            const short* wqr = &wqL[(16 * ct + lr) * 64 + lq * 8];
            short8v wq0 = *(const short8v*)wqr, wq1 = *(const short8v*)(wqr + 32);
            f32x4 qb = *(const f32x4*)&b_qkv[L * 192 + 16 * ct + lq * 4];
            #pragma unroll
            for (int mt = 0; mt < Mt; ++mt) {
                const short* yr = &ybuf[(16 * mt + lr) * 72 + lq * 8];
                short8v y0 = *(const short8v*)yr, y1 = *(const short8v*)(yr + 32);
                f32x4 acc = mfma32(wq0, y0, zero4);
                acc = mfma32(wq1, y1, acc);
                unsigned qa = pk2((acc[0] + qb[0]) * SCL2E, (acc[1] + qb[1]) * SCL2E);
                unsigned qc = pk2((acc[2] + qb[2]) * SCL2E, (acc[3] + qb[3]) * SCL2E);
                unsigned u0 = (unsigned)__shfl((int)qa, srcl);
                unsigned u1 = (unsigned)__shfl((int)qc, srcl);
                uint2v qv; qv.x = (l < 32) ? u0 : 0u; qv.y = (l < 32) ? u1 : 0u;
                qf[mt] = qv;
            }
        }
        // scores + softmax + PV, per query tile (no barriers; all in-wave)
        for (int mt = 0; mt < Mt; ++mt) {
            short4v qv = __builtin_bit_cast(short4v, qf[mt]);
            uint2v pkk[Mt];
            float psA = 0.f, psB = 0.f;
            #pragma unroll
            for (int jt = 0; jt < Mt; ++jt) {
                f32x4 s = mfma16(__builtin_bit_cast(short4v, kf[jt]), qv, zero4);
                float e0 = exp2fast(s[0]), e1 = exp2fast(s[1]);
                float e2 = exp2fast(s[2]), e3 = exp2fast(s[3]);
                if (jt == Mt - 1) {   // only the last tile contains pad keys
                    const int j0 = 16 * jt + lq * 4;
                    e0 = (j0 + 0 < N) ? e0 : 0.f;
                    e1 = (j0 + 1 < N) ? e1 : 0.f;
                    e2 = (j0 + 2 < N) ? e2 : 0.f;
                    e3 = (j0 + 3 < N) ? e3 : 0.f;
                }
                psA += e0 + e1; psB += e2 + e3;
                uint2v pv; pv.x = pk2(e0, e1); pv.y = pk2(e2, e3);
                pkk[jt] = pv;
            }
            float psum = psA + psB;
            float den = psum + __shfl_xor(psum, 16);
            den += __shfl_xor(den, 32);
            const float dinv = rcpfast(den);
            f32x4 po0 = zero4, po1 = zero4;
            #pragma unroll
            for (int jt = 0; jt < Mt; ++jt) {
                short4v bv = __builtin_bit_cast(short4v, pkk[jt]);
                if (jt & 1) po1 = mfma16(vf[jt], bv, po1);
                else        po0 = mfma16(vf[jt], bv, po0);
            }
            if ((lq >> 1) == a) {
                const int i = 16 * mt + lr;
                if (i < N) {
                    unsigned q0 = pk2((po0[0] + po1[0]) * dinv, (po0[1] + po1[1]) * dinv);
                    unsigned q1 = pk2((po0[2] + po1[2]) * dinv, (po0[3] + po1[3]) * dinv);
                    unsigned* dst = (unsigned*)&abuf[i * 72 + h * 8 + (lq & 1) * 4];
                    dst[0] = q0; dst[1] = q1;
                }
            }
        }
    }
    __syncthreads();

    // ---- phase D (fused, wave-local): w_o + residual + LN2 + MLP + residual
    //      + LN1-of-next-layer written into ybuf. wave = M-tile. ----
    {
        if (wv < Mt) {
            const int mt = wv;
            const int i = 16 * mt + lr;          // token (this layer)
            const bool iok = (i < N);
            const int xrow = iok ? (i / P + L) * 9 + (i % P) + L : 0;
            float* xp = xs + xrow * 68;
            const short* yr = &abuf[i * 72 + lq * 8];
            short8v y0 = *(const short8v*)yr;
            short8v y1 = *(const short8v*)(yr + 32);
            const short* woL = ws + WS_WO + L * 4096;
            f32x4 xv[4];
            #pragma unroll
            for (int ctp = 0; ctp < 4; ++ctp) {
                const short* wr = &woL[(16 * ctp + lr) * 64 + lq * 8];
                f32x4 acc = mfma32(*(const short8v*)wr, y0, zero4);
                acc = mfma32(*(const short8v*)(wr + 32), y1, acc);
                f32x4 bo = *(const f32x4*)&b_o[L * 64 + 16 * ctp + 4 * lq];
                f32x4 xc = zero4;
                if (iok) xc = *(const f32x4*)(xp + 16 * ctp + 4 * lq);
                #pragma unroll
                for (int rg = 0; rg < 4; ++rg) xc[rg] += acc[rg] + bo[rg];
                xv[ctp] = xc;
            }
            float s1, s2;
            stats_tree<4>(xv, s1, s2);
            s1 += __shfl_xor(s1, 16); s2 += __shfl_xor(s2, 16);
            s1 += __shfl_xor(s1, 32); s2 += __shfl_xor(s2, 32);
            const float m = s1 * 0.015625f;
            const float r = rsqrtf(s2 * 0.015625f - m * m + 1e-5f);
            unsigned* abw = (unsigned*)&abuf[i * 72];
            #pragma unroll
            for (int ctp = 0; ctp < 4; ++ctp) {
                f32x4 g  = *(const f32x4*)&ln2_g[L * 64 + 16 * ctp + 4 * lq];
                f32x4 bb = *(const f32x4*)&ln2_b[L * 64 + 16 * ctp + 4 * lq];
                abw[8 * ctp + 2 * lq]     = pk2((xv[ctp][0]-m)*r*g[0]+bb[0],
                                                (xv[ctp][1]-m)*r*g[1]+bb[1]);
                abw[8 * ctp + 2 * lq + 1] = pk2((xv[ctp][2]-m)*r*g[2]+bb[2],
                                                (xv[ctp][3]-m)*r*g[3]+bb[3]);
            }
            // MLP up (same-wave LDS round-trip, matched unsigned types)
            uint4v ua0 = *(const uint4v*)(abw + 4 * lq);
            uint4v ua1 = *(const uint4v*)(abw + 16 + 4 * lq);
            const short* w1L = ws + WS_W1 + L * 1024;
            short8v a10 = __builtin_bit_cast(short8v, ua0);
            short8v a11 = __builtin_bit_cast(short8v, ua1);
            short8v b10 = *(const short8v*)&w1L[lr * 64 + lq * 8];
            short8v b11 = *(const short8v*)&w1L[lr * 64 + lq * 8 + 32];
            f32x4 hA = mfma32(a10, b10, zero4);
            hA = mfma32(a11, b11, hA);
            if (lr < 8) {
                const float bg = b1[L * 8 + lr];
                #pragma unroll
                for (int rg = 0; rg < 4; ++rg)
                    hb[(16 * mt + 4 * lq + rg) * 8 + lr] = bf1(gelu_f(hA[rg] + bg));
            }
            // MLP down, swapped orientation: D[ch 16ctp+4lq+rg][tok lr]
            short8v hbf = (lq == 0) ? *(const short8v*)&hb[(16 * mt + lr) * 8] : zero8;
            const short* w2L = ws + WS_W2 + L * 512;
            f32x4 xf[4];
            #pragma unroll
            for (int ctp = 0; ctp < 4; ++ctp) {
                short8v a2 = (lq == 0) ? *(const short8v*)&w2L[(16 * ctp + lr) * 8] : zero8;
                f32x4 dacc = mfma32(a2, hbf, zero4);
                f32x4 b2v = *(const f32x4*)&b2[L * 64 + 16 * ctp + 4 * lq];
                #pragma unroll
                for (int rg = 0; rg < 4; ++rg) xf[ctp][rg] = xv[ctp][rg] + dacc[rg] + b2v[rg];
                if (iok) *(f32x4*)(xp + 16 * ctp + 4 * lq) = xf[ctp];
            }
            if (!LAST) {
                // LN1 of the next layer, straight from registers -> ybuf
                float t1, t2;
                stats_tree<4>(xf, t1, t2);
                t1 += __shfl_xor(t1, 16); t2 += __shfl_xor(t2, 16);
                t1 += __shfl_xor(t1, 32); t2 += __shfl_xor(t2, 32);
                const float mn = t1 * 0.015625f;
                const float rn = rsqrtf(t2 * 0.015625f - mn * mn + 1e-5f);
                const int r_ = i / P, c_ = i % P;
                const bool vok = iok && r_ >= 1 && r_ <= P - 2 && c_ >= 1 && c_ <= P - 2;
                if (vok) {
                    const int j = (r_ - 1) * (P - 2) + (c_ - 1);
                    unsigned* yw = (unsigned*)&ybuf[j * 72];
                    #pragma unroll
                    for (int ctp = 0; ctp < 4; ++ctp) {
                        f32x4 g  = *(const f32x4*)&ln1_g[(L + 1) * 64 + 16 * ctp + 4 * lq];
                        f32x4 bb = *(const f32x4*)&ln1_b[(L + 1) * 64 + 16 * ctp + 4 * lq];
                        yw[8 * ctp + 2 * lq]     = pk2((xf[ctp][0]-mn)*rn*g[0]+bb[0],
                                                       (xf[ctp][1]-mn)*rn*g[1]+bb[1]);
                        yw[8 * ctp + 2 * lq + 1] = pk2((xf[ctp][2]-mn)*rn*g[2]+bb[2],
                                                       (xf[ctp][3]-mn)*rn*g[3]+bb[3]);
                    }
                }
            }
        } else if (!LAST && wv == Mt) {
            // zero next layer's pad rows [Nn, 16*Mtn) in ybuf
            constexpr int Pn = P - 2, Nn = Pn * Pn, Mtn = (Nn + 15) / 16;
            constexpr int PadU = (16 * Mtn - Nn) * 36;
            unsigned* zb = (unsigned*)(ybuf + Nn * 72);
            for (int z = l; z < PadU; z += 64) zb[z] = 0;
        }
    }
    __syncthreads();

    if (LAST) {
        for (int idx = t; idx < 576; idx += NT) {
            const int d = idx / 9, rc = idx % 9;
            const int row = (rc / 3 + 3) * 9 + rc % 3 + 3;
            out[(size_t)b * 576 + idx] = xs[row * 68 + d];
        }
    }
}

__global__ __launch_bounds__(NT, 8) void vit_kernel(
    const float* __restrict__ x_in, const short* __restrict__ ws,
    const float* __restrict__ b_qkv, const float* __restrict__ b_o,
    const float* __restrict__ ln1_g, const float* __restrict__ ln1_b,
    const float* __restrict__ ln2_g, const float* __restrict__ ln2_b,
    const float* __restrict__ b1,    const float* __restrict__ b2,
    float* __restrict__ out)
{
    __shared__ __align__(16) float xs[81 * 68];     // 22032 B
    __shared__ __align__(16) short ybuf[96 * 72];   // 13824 B  (LN1 in)
    __shared__ __align__(16) short abuf[96 * 72];   // 13824 B  (attn out)
    __shared__ __align__(16) short hb[96 * 8];      //  1536 B  (MLP hidden)

    const int b = blockIdx.x;
    const int t = threadIdx.x;

    // zero abuf once: phase D reads pad rows (outputs masked; keep finite)
    for (int idx = t; idx < 96 * 72; idx += NT) abuf[idx] = 0;

    const float* xin = x_in + (size_t)b * 5184;
    for (int q4 = t; q4 < 1296; q4 += NT) {
        const int i = q4 >> 4, dq = q4 & 15;
        *(f32x4*)&xs[i * 68 + dq * 4] = *(const f32x4*)&xin[i * 64 + dq * 4];
    }
    __syncthreads();

    layer_fn<81, 9, 0, true,  false>(xs, ybuf, abuf, hb, ws, b_qkv, b_o,
                                     ln1_g, ln1_b, ln2_g, ln2_b, b1, b2, out, b, t);
    layer_fn<49, 7, 1, false, false>(xs, ybuf, abuf, hb, ws, b_qkv, b_o,
                                     ln1_g, ln1_b, ln2_g, ln2_b, b1, b2, out, b, t);
    layer_fn<25, 5, 2, false, false>(xs, ybuf, abuf, hb, ws, b_qkv, b_o,
                                     ln1_g, ln1_b, ln2_g, ln2_b, b1, b2, out, b, t);
    layer_fn<9,  3, 3, false, true >(xs, ybuf, abuf, hb, ws, b_qkv, b_o,
                                     ln1_g, ln1_b, ln2_g, ln2_b, b1, b2, out, b, t);
}

extern "C" void kernel_launch(void* const* d_in, const int* in_sizes, int n_in,
                              void* d_out, int out_size, void* d_ws, size_t ws_size,
                              hipStream_t stream) {
    (void)n_in; (void)out_size; (void)ws_size;
    const float* x     = (const float*)d_in[0];
    const float* w_qkv = (const float*)d_in[1];
    const float* b_qkv = (const float*)d_in[2];
    const float* w_o   = (const float*)d_in[3];
    const float* b_o   = (const float*)d_in[4];
    const float* ln1_g = (const float*)d_in[5];
    const float* ln1_b = (const float*)d_in[6];
    const float* ln2_g = (const float*)d_in[7];
    const float* ln2_b = (const float*)d_in[8];
    const float* w1    = (const float*)d_in[9];
    const float* b1    = (const float*)d_in[10];
    const float* w2    = (const float*)d_in[11];
    const float* b2    = (const float*)d_in[12];
    short* ws = (short*)d_ws;

    prep_kernel<<<dim3((WS_TOT + 255) / 256), dim3(256), 0, stream>>>(w_qkv, w_o, w1, w2, ws);

    int B = in_sizes[0] / (81 * 64);
    vit_kernel<<<dim3(B), dim3(NT), 0, stream>>>(
        x, ws, b_qkv, b_o, ln1_g, ln1_b, ln2_g, ln2_b, b1, b2, (float*)d_out);
}

// Round 14
// 372.205 us; speedup vs baseline: 1.2502x; 1.2502x over previous
//
#include <hip/hip_runtime.h>
#include <hip/hip_bf16.h>
#include <math.h>

#define NT 512

typedef __attribute__((ext_vector_type(8))) short short8v;
typedef __attribute__((ext_vector_type(4))) short short4v;
typedef __attribute__((ext_vector_type(4))) float f32x4;
typedef __attribute__((ext_vector_type(2))) unsigned uint2v;
typedef __attribute__((ext_vector_type(4))) unsigned uint4v;

__device__ __forceinline__ unsigned short f2bf(float x) {   // prep kernel only
    unsigned u = __float_as_uint(x);
    unsigned r = ((u >> 16) & 1u) + 0x7FFFu;
    return (unsigned short)((u + r) >> 16);
}
__device__ __forceinline__ unsigned pk2(float a, float b) {
    __hip_bfloat162 h = __float22bfloat162_rn(make_float2(a, b));
    unsigned r;
    __builtin_memcpy(&r, &h, sizeof(r));
    return r;
}
__device__ __forceinline__ short bf1(float a) {
    __hip_bfloat16 h = __float2bfloat16(a);
    short r;
    __builtin_memcpy(&r, &h, sizeof(r));
    return r;
}
__device__ __forceinline__ float exp2fast(float x) {
#if __has_builtin(__builtin_amdgcn_exp2f)
    return __builtin_amdgcn_exp2f(x);
#else
    return exp2f(x);
#endif
}
__device__ __forceinline__ float rcpfast(float x) {
#if __has_builtin(__builtin_amdgcn_rcpf)
    return __builtin_amdgcn_rcpf(x);
#else
    return 1.0f / x;
#endif
}
// tanh-form gelu via exp2 + rcp (|err| vs erf-gelu ~3e-3, inside tolerance)
__device__ __forceinline__ float gelu_f(float x) {
    float x3 = x * x * x;
    float e = exp2fast(-2.3022079f * x - 0.1029432f * x3);
    return x * rcpfast(1.0f + e);
}
__device__ __forceinline__ f32x4 mfma32(short8v a, short8v b, f32x4 c) {
    return __builtin_amdgcn_mfma_f32_16x16x32_bf16(a, b, c, 0, 0, 0);
}

// tree reductions (avoid serial FP chains; fp adds are not reassociable by default)
template<int M>
__device__ __forceinline__ float sum_tree(const f32x4* a) {
    float p[M];
    #pragma unroll
    for (int i = 0; i < M; ++i)
        p[i] = (a[i][0] + a[i][1]) + (a[i][2] + a[i][3]);
    #pragma unroll
    for (int s = 1; s < M; s *= 2)
        #pragma unroll
        for (int i = 0; i + s < M; i += 2 * s) p[i] += p[i + s];
    return p[0];
}
template<int M>
__device__ __forceinline__ void stats_tree(const f32x4* v, float& s1o, float& s2o) {
    float a[M], b[M];
    #pragma unroll
    for (int i = 0; i < M; ++i) {
        a[i] = (v[i][0] + v[i][1]) + (v[i][2] + v[i][3]);
        float q0 = v[i][0] * v[i][0], q1 = v[i][1] * v[i][1];
        float q2 = v[i][2] * v[i][2], q3 = v[i][3] * v[i][3];
        b[i] = (q0 + q1) + (q2 + q3);
    }
    #pragma unroll
    for (int s = 1; s < M; s *= 2)
        #pragma unroll
        for (int i = 0; i + s < M; i += 2 * s) { a[i] += a[i + s]; b[i] += b[i + s]; }
    s1o = a[0]; s2o = b[0];
}

// ws layout (bf16 shorts): wqkvT[L][192][64] @0 ; woT[L][64][64] @49152 ;
//                          w1T[L][16][64] @65536 (rows j>=8 zero) ; w2T[L][64][8] @69632
#define WS_WO 49152
#define WS_W1 65536
#define WS_W2 69632
#define WS_TOT 71680

__global__ __launch_bounds__(256) void prep_kernel(
    const float* __restrict__ w_qkv, const float* __restrict__ w_o,
    const float* __restrict__ w1, const float* __restrict__ w2,
    short* __restrict__ ws)
{
    int idx = blockIdx.x * 256 + threadIdx.x;
    if (idx < WS_WO) {
        int l = idx / 12288, r = idx % 12288, c = r >> 6, d = r & 63;
        ws[idx] = (short)f2bf(w_qkv[l * 12288 + d * 192 + c]);
    } else if (idx < WS_W1) {
        int k = idx - WS_WO; int l = k / 4096, r = k % 4096, c = r >> 6, d = r & 63;
        ws[idx] = (short)f2bf(w_o[l * 4096 + d * 64 + c]);
    } else if (idx < WS_W2) {
        int k = idx - WS_W1; int l = k / 1024, r = k % 1024, j = r >> 6, d = r & 63;
        ws[idx] = (j < 8) ? (short)f2bf(w1[l * 512 + d * 8 + j]) : (short)0;
    } else if (idx < WS_TOT) {
        int k = idx - WS_W2; int l = k / 512, r = k % 512, c = r >> 3, j = r & 7;
        ws[idx] = (short)f2bf(w2[l * 512 + j * 64 + c]);
    }
}

// Buffer rotation per layer: y region (LN1-in + attn-out, stride 72) and v region
// (vT stride 104; reused at end of phase D as next layer's LN1-out, stride 72).
// qbf/kbf fixed. xs fp32 [81][68] full 9x9 grid, ring-indexed per layer.
template<int N, int P, int L, bool FIRST, bool LAST>
__device__ __forceinline__ void layer_fn(
    float* __restrict__ xs, short* __restrict__ y, short* __restrict__ vb,
    short* __restrict__ qbf, short* __restrict__ kbf,
    const short* __restrict__ ws,
    const float* __restrict__ b_qkv, const float* __restrict__ b_o,
    const float* __restrict__ ln1_g, const float* __restrict__ ln1_b,
    const float* __restrict__ ln2_g, const float* __restrict__ ln2_b,
    const float* __restrict__ b1,    const float* __restrict__ b2,
    float* __restrict__ out, int b, int t)
{
    constexpr int Mt = (N + 15) / 16;
    constexpr float SCL2E = 0.51010905835f;   // (HEAD_DIM/HEADS)^-0.5 * log2(e)
    const int wv = t >> 6, l = t & 63, lr = l & 15, lq = l >> 4;
    short8v zero8 = {};
    f32x4 zero4 = {0.f, 0.f, 0.f, 0.f};

    // ---- phase A (first layer only): LN1 -> y. 4 lanes per token ----
    if (FIRST) {
        if (t < 64 * Mt) {
            const int token = t >> 2, part = t & 3, d0 = part * 16;
            short* yrow = y + token * 72 + d0;
            if (token < N) {
                const int row = (token / P + L) * 9 + token % P + L;
                const float* xr = xs + row * 68 + d0;
                f32x4 v[4];
                #pragma unroll
                for (int k = 0; k < 4; ++k) v[k] = *(const f32x4*)(xr + 4 * k);
                float s1, s2;
                stats_tree<4>(v, s1, s2);
                s1 += __shfl_xor(s1, 1); s2 += __shfl_xor(s2, 1);
                s1 += __shfl_xor(s1, 2); s2 += __shfl_xor(s2, 2);
                const float m = s1 * 0.015625f;
                const float r = rsqrtf(s2 * 0.015625f - m * m + 1e-5f);
                uint4v w0, w1v;
                #pragma unroll
                for (int k = 0; k < 4; ++k) {
                    f32x4 g  = *(const f32x4*)&ln1_g[L * 64 + d0 + 4 * k];
                    f32x4 bb = *(const f32x4*)&ln1_b[L * 64 + d0 + 4 * k];
                    unsigned p0 = pk2((v[k][0]-m)*r*g[0]+bb[0], (v[k][1]-m)*r*g[1]+bb[1]);
                    unsigned p1 = pk2((v[k][2]-m)*r*g[2]+bb[2], (v[k][3]-m)*r*g[3]+bb[3]);
                    if (k == 0) { w0.x = p0; w0.y = p1; }
                    else if (k == 1) { w0.z = p0; w0.w = p1; }
                    else if (k == 2) { w1v.x = p0; w1v.y = p1; }
                    else { w1v.z = p0; w1v.w = p1; }
                }
                *(uint4v*)yrow = w0;
                *(uint4v*)(yrow + 8) = w1v;
            } else {
                uint4v z = {};
                *(uint4v*)yrow = z;
                *(uint4v*)(yrow + 8) = z;
            }
        }
        __syncthreads();
    }

    // ---- phase B: qkv GEMM. q/k operand-swapped (lane=token, packed writes);
    //      v unswapped (lane=channel) -> vb stride 104. q scale = SC*log2e. ----
    {
        const short* wqL = ws + L * 12288;
        for (int u = wv; u < Mt * 12; u += 8) {
            const int mt = u / 12, ct = u - mt * 12;
            const short* yr = &y[(16 * mt + lr) * 72 + lq * 8];
            short8v y0 = *(const short8v*)yr, y1 = *(const short8v*)(yr + 32);
            const short* wr = &wqL[(16 * ct + lr) * 64 + lq * 8];
            short8v w0 = *(const short8v*)wr, w1 = *(const short8v*)(wr + 32);
            if (ct < 8) {
                f32x4 acc = mfma32(w0, y0, zero4);
                acc = mfma32(w1, y1, acc);
                f32x4 bq = *(const f32x4*)&b_qkv[L * 192 + 16 * ct + lq * 4];
                const int i = 16 * mt + lr;   // token
                if (ct < 4) {
                    unsigned p0 = pk2((acc[0]+bq[0])*SCL2E, (acc[1]+bq[1])*SCL2E);
                    unsigned p1 = pk2((acc[2]+bq[2])*SCL2E, (acc[3]+bq[3])*SCL2E);
                    unsigned* dst = (unsigned*)&qbf[i * 72 + 16 * ct + lq * 4];
                    dst[0] = p0; dst[1] = p1;
                } else {
                    unsigned p0 = pk2(acc[0]+bq[0], acc[1]+bq[1]);
                    unsigned p1 = pk2(acc[2]+bq[2], acc[3]+bq[3]);
                    unsigned* dst = (unsigned*)&kbf[i * 72 + 16 * (ct - 4) + lq * 4];
                    dst[0] = p0; dst[1] = p1;
                }
            } else {
                f32x4 acc = mfma32(y0, w0, zero4);
                acc = mfma32(y1, w1, acc);
                const int cv = 16 * (ct - 8) + lr;   // v channel
                const float bias = b_qkv[L * 192 + 128 + cv];
                unsigned p0 = pk2(acc[0]+bias, acc[1]+bias);
                unsigned p1 = pk2(acc[2]+bias, acc[3]+bias);
                unsigned* dst = (unsigned*)&vb[cv * 104 + 16 * mt + lq * 4];
                dst[0] = p0; dst[1] = p1;
            }
        }
    }
    __syncthreads();

    // ---- phase C: attention. wave = head; K/V hoisted. Manual 2-stage pipeline:
    //      SCORES(mt+1) issued before FINISH(mt) so the next tile's MFMAs and
    //      LDS q-load overlap the current tile's softmax/PV chain. Static
    //      even/odd buffers (sA/sB), fully unrolled -> all indices compile-time. ----
    {
        const int h = wv, hh = wv >> 1;
        short8v kf[Mt];
        #pragma unroll
        for (int jt = 0; jt < Mt; ++jt)
            kf[jt] = (l < 16) ? *(const short8v*)&kbf[(16 * jt + lr) * 72 + h * 8] : zero8;
#if __has_builtin(__builtin_amdgcn_mfma_f32_16x16x16bf16_1k)
        short4v vf[Mt];
        #pragma unroll
        for (int jt = 0; jt < Mt; ++jt)
            vf[jt] = *(const short4v*)&vb[(16 * hh + lr) * 104 + 16 * jt + lq * 4];
#else
        constexpr int KS2 = (Mt + 1) / 2;
        short8v vf8[KS2];
        #pragma unroll
        for (int ks = 0; ks < KS2; ++ks)
            vf8[ks] = *(const short8v*)&vb[(16 * hh + lr) * 104 + 32 * ks + lq * 8];
#endif
        auto SCORES = [&](int mt2, f32x4 (&acc)[Mt]) {
            short8v bq = (l < 16) ? *(const short8v*)&qbf[(16 * mt2 + lr) * 72 + h * 8] : zero8;
            #pragma unroll
            for (int jt = 0; jt < Mt; ++jt) acc[jt] = mfma32(kf[jt], bq, zero4);
        };
        auto FINISH = [&](int mt2, f32x4 (&acc)[Mt]) {
            #pragma unroll
            for (int jt = 0; jt < Mt; ++jt) {
                #pragma unroll
                for (int rg = 0; rg < 4; ++rg) {
                    float e = exp2fast(acc[jt][rg]);
                    if (jt == Mt - 1) {   // only the last tile contains pad keys
                        const int j = 16 * jt + lq * 4 + rg;
                        e = (j < N) ? e : 0.f;
                    }
                    acc[jt][rg] = e;
                }
            }
            float psum = sum_tree<Mt>(acc);
            float den = psum + __shfl_xor(psum, 16);
            den += __shfl_xor(den, 32);
            const float dinv = rcpfast(den);
            unsigned pkk[Mt][2];
            #pragma unroll
            for (int jt = 0; jt < Mt; ++jt) {
                pkk[jt][0] = pk2(acc[jt][0], acc[jt][1]);
                pkk[jt][1] = pk2(acc[jt][2], acc[jt][3]);
            }
            f32x4 po0 = zero4, po1 = zero4;
#if __has_builtin(__builtin_amdgcn_mfma_f32_16x16x16bf16_1k)
            #pragma unroll
            for (int jt = 0; jt < Mt; ++jt) {
                uint2v pw; pw.x = pkk[jt][0]; pw.y = pkk[jt][1];
                short4v bv = __builtin_bit_cast(short4v, pw);
                if (jt & 1) po1 = __builtin_amdgcn_mfma_f32_16x16x16bf16_1k(vf[jt], bv, po1, 0, 0, 0);
                else        po0 = __builtin_amdgcn_mfma_f32_16x16x16bf16_1k(vf[jt], bv, po0, 0, 0, 0);
            }
#else
            #pragma unroll
            for (int ks = 0; ks < KS2; ++ks) {
                const int t1ok = (2 * ks + 1) < Mt;
                unsigned pA0 = pkk[2 * ks][0], pA1 = pkk[2 * ks][1];
                unsigned pB0 = t1ok ? pkk[2 * ks + 1][0] : 0u;
                unsigned pB1 = t1ok ? pkk[2 * ks + 1][1] : 0u;
                int i01 = ((((lq & 1) * 2) * 16) + lr) * 4;
                int i23 = ((((lq & 1) * 2 + 1) * 16) + lr) * 4;
                unsigned w0a = (unsigned)__builtin_amdgcn_ds_bpermute(i01, (int)pA0);
                unsigned w0b = (unsigned)__builtin_amdgcn_ds_bpermute(i01, (int)pB0);
                unsigned w1a = (unsigned)__builtin_amdgcn_ds_bpermute(i01, (int)pA1);
                unsigned w1b = (unsigned)__builtin_amdgcn_ds_bpermute(i01, (int)pB1);
                unsigned w2a = (unsigned)__builtin_amdgcn_ds_bpermute(i23, (int)pA0);
                unsigned w2b = (unsigned)__builtin_amdgcn_ds_bpermute(i23, (int)pB0);
                unsigned w3a = (unsigned)__builtin_amdgcn_ds_bpermute(i23, (int)pA1);
                unsigned w3b = (unsigned)__builtin_amdgcn_ds_bpermute(i23, (int)pB1);
                uint4v wv4;
                wv4.x = (lq >> 1) ? w0b : w0a;
                wv4.y = (lq >> 1) ? w1b : w1a;
                wv4.z = (lq >> 1) ? w2b : w2a;
                wv4.w = (lq >> 1) ? w3b : w3a;
                short8v bv = __builtin_bit_cast(short8v, wv4);
                po0 = mfma32(vf8[ks], bv, po0);
            }
#endif
            if ((lq >> 1) == (h & 1)) {
                const int i = 16 * mt2 + lr;
                if (i < N) {
                    unsigned q0 = pk2((po0[0]+po1[0])*dinv, (po0[1]+po1[1])*dinv);
                    unsigned q1 = pk2((po0[2]+po1[2])*dinv, (po0[3]+po1[3])*dinv);
                    unsigned* dst = (unsigned*)&y[i * 72 + h * 8 + (lq & 1) * 4];
                    dst[0] = q0; dst[1] = q1;
                }
            }
        };
        f32x4 sA[Mt], sB[Mt];
        SCORES(0, sA);
        #pragma unroll
        for (int mt = 0; mt < Mt; ++mt) {
            if (mt & 1) {
                if (mt + 1 < Mt) SCORES(mt + 1, sA);
                FINISH(mt, sB);
            } else {
                if (mt + 1 < Mt) SCORES(mt + 1, sB);
                FINISH(mt, sA);
            }
        }
    }
    __syncthreads();

    // ---- phase D (fused, wave-local): w_o + residual + LN2 + MLP + residual
    //      + LN1-of-next-layer written into vb (v region is dead here). ----
    {
        short* hb = qbf;   // qbf dead after attention
        if (wv < Mt) {
            const int mt = wv;
            const int i = 16 * mt + lr;          // token (this layer)
            const bool iok = (i < N);
            const int xrow = iok ? (i / P + L) * 9 + (i % P) + L : 0;
            float* xp = xs + xrow * 68;
            const short* yr = &y[i * 72 + lq * 8];
            short8v y0 = *(const short8v*)yr;
            short8v y1 = *(const short8v*)(yr + 32);
            const short* woL = ws + WS_WO + L * 4096;
            f32x4 xv[4];
            #pragma unroll
            for (int ct = 0; ct < 4; ++ct) {
                const short* wr = &woL[(16 * ct + lr) * 64 + lq * 8];
                f32x4 acc = mfma32(*(const short8v*)wr, y0, zero4);
                acc = mfma32(*(const short8v*)(wr + 32), y1, acc);
                f32x4 bo = *(const f32x4*)&b_o[L * 64 + 16 * ct + 4 * lq];
                f32x4 xc = zero4;
                if (iok) xc = *(const f32x4*)(xp + 16 * ct + 4 * lq);
                #pragma unroll
                for (int rg = 0; rg < 4; ++rg) xc[rg] += acc[rg] + bo[rg];
                xv[ct] = xc;
            }
            float s1, s2;
            stats_tree<4>(xv, s1, s2);
            s1 += __shfl_xor(s1, 16); s2 += __shfl_xor(s2, 16);
            s1 += __shfl_xor(s1, 32); s2 += __shfl_xor(s2, 32);
            const float m = s1 * 0.015625f;
            const float r = rsqrtf(s2 * 0.015625f - m * m + 1e-5f);
            unsigned* ybw = (unsigned*)&y[i * 72];
            #pragma unroll
            for (int ct = 0; ct < 4; ++ct) {
                f32x4 g  = *(const f32x4*)&ln2_g[L * 64 + 16 * ct + 4 * lq];
                f32x4 bb = *(const f32x4*)&ln2_b[L * 64 + 16 * ct + 4 * lq];
                ybw[8 * ct + 2 * lq]     = pk2((xv[ct][0]-m)*r*g[0]+bb[0],
                                               (xv[ct][1]-m)*r*g[1]+bb[1]);
                ybw[8 * ct + 2 * lq + 1] = pk2((xv[ct][2]-m)*r*g[2]+bb[2],
                                               (xv[ct][3]-m)*r*g[3]+bb[3]);
            }
            // MLP up
            uint4v ua0 = *(const uint4v*)(ybw + 4 * lq);
            uint4v ua1 = *(const uint4v*)(ybw + 16 + 4 * lq);
            const short* w1L = ws + WS_W1 + L * 1024;
            short8v a10 = __builtin_bit_cast(short8v, ua0);
            short8v a11 = __builtin_bit_cast(short8v, ua1);
            short8v b10 = *(const short8v*)&w1L[lr * 64 + lq * 8];
            short8v b11 = *(const short8v*)&w1L[lr * 64 + lq * 8 + 32];
            f32x4 hA = mfma32(a10, b10, zero4);
            hA = mfma32(a11, b11, hA);
            if (lr < 8) {
                const float bg = b1[L * 8 + lr];
                #pragma unroll
                for (int rg = 0; rg < 4; ++rg)
                    hb[(16 * mt + 4 * lq + rg) * 8 + lr] = bf1(gelu_f(hA[rg] + bg));
            }
            // MLP down, swapped orientation: D[ch 16ct+4lq+rg][tok lr]
            short8v hbf = (lq == 0) ? *(const short8v*)&hb[(16 * mt + lr) * 8] : zero8;
            const short* w2L = ws + WS_W2 + L * 512;
            f32x4 xf[4];
            #pragma unroll
            for (int ct = 0; ct < 4; ++ct) {
                short8v a2 = (lq == 0) ? *(const short8v*)&w2L[(16 * ct + lr) * 8] : zero8;
                f32x4 dacc = mfma32(a2, hbf, zero4);
                f32x4 b2v = *(const f32x4*)&b2[L * 64 + 16 * ct + 4 * lq];
                #pragma unroll
                for (int rg = 0; rg < 4; ++rg) xf[ct][rg] = xv[ct][rg] + dacc[rg] + b2v[rg];
                if (iok) *(f32x4*)(xp + 16 * ct + 4 * lq) = xf[ct];
            }
            if (!LAST) {
                // LN1 of the next layer, straight from registers -> vb (stride 72)
                float t1, t2;
                stats_tree<4>(xf, t1, t2);
                t1 += __shfl_xor(t1, 16); t2 += __shfl_xor(t2, 16);
                t1 += __shfl_xor(t1, 32); t2 += __shfl_xor(t2, 32);
                const float mn = t1 * 0.015625f;
                const float rn = rsqrtf(t2 * 0.015625f - mn * mn + 1e-5f);
                const int r_ = i / P, c_ = i % P;
                const bool vok = iok && r_ >= 1 && r_ <= P - 2 && c_ >= 1 && c_ <= P - 2;
                if (vok) {
                    const int j = (r_ - 1) * (P - 2) + (c_ - 1);
                    unsigned* yw = (unsigned*)&vb[j * 72];
                    #pragma unroll
                    for (int ct = 0; ct < 4; ++ct) {
                        f32x4 g  = *(const f32x4*)&ln1_g[(L + 1) * 64 + 16 * ct + 4 * lq];
                        f32x4 bb = *(const f32x4*)&ln1_b[(L + 1) * 64 + 16 * ct + 4 * lq];
                        yw[8 * ct + 2 * lq]     = pk2((xf[ct][0]-mn)*rn*g[0]+bb[0],
                                                      (xf[ct][1]-mn)*rn*g[1]+bb[1]);
                        yw[8 * ct + 2 * lq + 1] = pk2((xf[ct][2]-mn)*rn*g[2]+bb[2],
                                                      (xf[ct][3]-mn)*rn*g[3]+bb[3]);
                    }
                }
            }
        } else if (!LAST && wv == Mt) {
            // zero next layer's pad rows [Nn, 16*Mtn) in vb
            constexpr int Pn = P - 2, Nn = Pn * Pn, Mtn = (Nn + 15) / 16;
            constexpr int PadU = (16 * Mtn - Nn) * 36;
            unsigned* zb = (unsigned*)(vb + Nn * 72);
            for (int z = l; z < PadU; z += 64) zb[z] = 0;
        }
    }
    __syncthreads();

    if (LAST) {
        for (int idx = t; idx < 576; idx += NT) {
            const int d = idx / 9, rc = idx % 9;
            const int row = (rc / 3 + 3) * 9 + rc % 3 + 3;
            out[(size_t)b * 576 + idx] = xs[row * 68 + d];
        }
    }
}

__global__ __launch_bounds__(NT, 4) void vit_kernel(
    const float* __restrict__ x_in, const short* __restrict__ ws,
    const float* __restrict__ b_qkv, const float* __restrict__ b_o,
    const float* __restrict__ ln1_g, const float* __restrict__ ln1_b,
    const float* __restrict__ ln2_g, const float* __restrict__ ln2_b,
    const float* __restrict__ b1,    const float* __restrict__ b2,
    float* __restrict__ out)
{
    __shared__ __align__(16) float xs[81 * 68];
    __shared__ __align__(16) short ybf[96 * 72];   // region R0
    __shared__ __align__(16) short vbuf[64 * 104]; // region R1
    __shared__ __align__(16) short qbf[96 * 72];
    __shared__ __align__(16) short kbf[96 * 72];

    const int b = blockIdx.x;
    const int t = threadIdx.x;

    // one-time zero of the v region (stale-read robustness: pad cols/rows)
    for (int idx = t; idx < 64 * 104; idx += NT) vbuf[idx] = 0;

    const float* xin = x_in + (size_t)b * 5184;
    for (int q4 = t; q4 < 1296; q4 += NT) {
        const int i = q4 >> 4, dq = q4 & 15;
        *(f32x4*)&xs[i * 68 + dq * 4] = *(const f32x4*)&xin[i * 64 + dq * 4];
    }
    __syncthreads();

    // buffer rotation: L0 y=R0 v=R1; L1 y=R1 v=R0; L2 y=R0 v=R1; L3 y=R1 v=R0
    layer_fn<81, 9, 0, true,  false>(xs, ybf,  vbuf, qbf, kbf, ws, b_qkv, b_o,
                                     ln1_g, ln1_b, ln2_g, ln2_b, b1, b2, out, b, t);
    layer_fn<49, 7, 1, false, false>(xs, vbuf, ybf,  qbf, kbf, ws, b_qkv, b_o,
                                     ln1_g, ln1_b, ln2_g, ln2_b, b1, b2, out, b, t);
    layer_fn<25, 5, 2, false, false>(xs, ybf,  vbuf, qbf, kbf, ws, b_qkv, b_o,
                                     ln1_g, ln1_b, ln2_g, ln2_b, b1, b2, out, b, t);
    layer_fn<9,  3, 3, false, true >(xs, vbuf, ybf,  qbf, kbf, ws, b_qkv, b_o,
                                     ln1_g, ln1_b, ln2_g, ln2_b, b1, b2, out, b, t);
}

extern "C" void kernel_launch(void* const* d_in, const int* in_sizes, int n_in,
                              void* d_out, int out_size, void* d_ws, size_t ws_size,
                              hipStream_t stream) {
    (void)n_in; (void)out_size; (void)ws_size;
    const float* x     = (const float*)d_in[0];
    const float* w_qkv = (const float*)d_in[1];
    const float* b_qkv = (const float*)d_in[2];
    const float* w_o   = (const float*)d_in[3];
    const float* b_o   = (const float*)d_in[4];
    const float* ln1_g = (const float*)d_in[5];
    const float* ln1_b = (const float*)d_in[6];
    const float* ln2_g = (const float*)d_in[7];
    const float* ln2_b = (const float*)d_in[8];
    const float* w1    = (const float*)d_in[9];
    const float* b1    = (const float*)d_in[10];
    const float* w2    = (const float*)d_in[11];
    const float* b2    = (const float*)d_in[12];
    short* ws = (short*)d_ws;

    prep_kernel<<<dim3((WS_TOT + 255) / 256), dim3(256), 0, stream>>>(w_qkv, w_o, w1, w2, ws);

    int B = in_sizes[0] / (81 * 64);
    vit_kernel<<<dim3(B), dim3(NT), 0, stream>>>(
        x, ws, b_qkv, b_o, ln1_g, ln1_b, ln2_g, ln2_b, b1, b2, (float*)d_out);
}

// Round 15
// 338.038 us; speedup vs baseline: 1.3766x; 1.1011x over previous
//
#include <hip/hip_runtime.h>
#include <hip/hip_bf16.h>
#include <math.h>

#define NT 512

typedef __attribute__((ext_vector_type(8))) short short8v;
typedef __attribute__((ext_vector_type(4))) short short4v;
typedef __attribute__((ext_vector_type(4))) float f32x4;
typedef __attribute__((ext_vector_type(2))) unsigned uint2v;
typedef __attribute__((ext_vector_type(4))) unsigned uint4v;

__device__ __forceinline__ unsigned short f2bf(float x) {   // prep kernel only
    unsigned u = __float_as_uint(x);
    unsigned r = ((u >> 16) & 1u) + 0x7FFFu;
    return (unsigned short)((u + r) >> 16);
}
__device__ __forceinline__ unsigned pk2(float a, float b) {
    __hip_bfloat162 h = __float22bfloat162_rn(make_float2(a, b));
    unsigned r;
    __builtin_memcpy(&r, &h, sizeof(r));
    return r;
}
__device__ __forceinline__ short bf1(float a) {
    __hip_bfloat16 h = __float2bfloat16(a);
    short r;
    __builtin_memcpy(&r, &h, sizeof(r));
    return r;
}
__device__ __forceinline__ float exp2fast(float x) {
#if __has_builtin(__builtin_amdgcn_exp2f)
    return __builtin_amdgcn_exp2f(x);
#else
    return exp2f(x);
#endif
}
__device__ __forceinline__ float rcpfast(float x) {
#if __has_builtin(__builtin_amdgcn_rcpf)
    return __builtin_amdgcn_rcpf(x);
#else
    return 1.0f / x;
#endif
}
// tanh-form gelu via exp2 + rcp (|err| vs erf-gelu ~3e-3, inside tolerance)
__device__ __forceinline__ float gelu_f(float x) {
    float x3 = x * x * x;
    float e = exp2fast(-2.3022079f * x - 0.1029432f * x3);
    return x * rcpfast(1.0f + e);
}
__device__ __forceinline__ f32x4 mfma32(short8v a, short8v b, f32x4 c) {
    return __builtin_amdgcn_mfma_f32_16x16x32_bf16(a, b, c, 0, 0, 0);
}
__device__ __forceinline__ f32x4 mfma16(short4v a, short4v b, f32x4 c) {
    return __builtin_amdgcn_mfma_f32_16x16x16bf16_1k(a, b, c, 0, 0, 0);
}

template<int M>
__device__ __forceinline__ void stats_tree(const f32x4* v, float& s1o, float& s2o) {
    float a[M], b[M];
    #pragma unroll
    for (int i = 0; i < M; ++i) {
        a[i] = (v[i][0] + v[i][1]) + (v[i][2] + v[i][3]);
        float q0 = v[i][0] * v[i][0], q1 = v[i][1] * v[i][1];
        float q2 = v[i][2] * v[i][2], q3 = v[i][3] * v[i][3];
        b[i] = (q0 + q1) + (q2 + q3);
    }
    #pragma unroll
    for (int s = 1; s < M; s *= 2)
        #pragma unroll
        for (int i = 0; i + s < M; i += 2 * s) { a[i] += a[i + s]; b[i] += b[i + s]; }
    s1o = a[0]; s2o = b[0];
}

// ws layout (bf16 shorts): wqkvT[L][192][64] @0 ; woT[L][64][64] @49152 ;
//                          w1T[L][16][64] @65536 (rows j>=8 zero) ; w2T[L][64][8] @69632
#define WS_WO 49152
#define WS_W1 65536
#define WS_W2 69632
#define WS_TOT 71680

__global__ __launch_bounds__(256) void prep_kernel(
    const float* __restrict__ w_qkv, const float* __restrict__ w_o,
    const float* __restrict__ w1, const float* __restrict__ w2,
    short* __restrict__ ws)
{
    int idx = blockIdx.x * 256 + threadIdx.x;
    if (idx < WS_WO) {
        int l = idx / 12288, r = idx % 12288, c = r >> 6, d = r & 63;
        ws[idx] = (short)f2bf(w_qkv[l * 12288 + d * 192 + c]);
    } else if (idx < WS_W1) {
        int k = idx - WS_WO; int l = k / 4096, r = k % 4096, c = r >> 6, d = r & 63;
        ws[idx] = (short)f2bf(w_o[l * 4096 + d * 64 + c]);
    } else if (idx < WS_W2) {
        int k = idx - WS_W1; int l = k / 1024, r = k % 1024, j = r >> 6, d = r & 63;
        ws[idx] = (j < 8) ? (short)f2bf(w1[l * 512 + d * 8 + j]) : (short)0;
    } else if (idx < WS_TOT) {
        int k = idx - WS_W2; int l = k / 512, r = k % 512, c = r >> 3, j = r & 7;
        ws[idx] = (short)f2bf(w2[l * 512 + j * 64 + c]);
    }
}

// LDS (51.2 KB -> 3 blocks/CU): xs fp32 [81][68] (full 9x9 grid, ring-indexed);
// ybuf bf16 [96][72] = LN1 input; qbf bf16 [96][72] = q (phase B) then attn-out
// (phase C overwrites per-head columns after use); hb bf16 [96][8] MLP hidden.
// k and v live in registers (per-wave GEMM, 2x duplicated across head pairs).
template<int N, int P, int L, bool FIRST, bool LAST>
__device__ __forceinline__ void layer_fn(
    float* __restrict__ xs, short* __restrict__ ybuf, short* __restrict__ qbf,
    short* __restrict__ hb, const short* __restrict__ ws,
    const float* __restrict__ b_qkv, const float* __restrict__ b_o,
    const float* __restrict__ ln1_g, const float* __restrict__ ln1_b,
    const float* __restrict__ ln2_g, const float* __restrict__ ln2_b,
    const float* __restrict__ b1,    const float* __restrict__ b2,
    float* __restrict__ out, int b, int t)
{
    constexpr int Mt = (N + 15) / 16;
    constexpr float SCL2E = 0.51010905835f;   // (HEAD_DIM/HEADS)^-0.5 * log2(e)
    const int wv = t >> 6, l = t & 63, lr = l & 15, lq = l >> 4;
    short8v zero8 = {};
    short4v zero4s = {};
    f32x4 zero4 = {0.f, 0.f, 0.f, 0.f};

    // ---- phase A (first layer only): LN1 -> ybuf. 4 lanes per token ----
    if (FIRST) {
        if (t < 64 * Mt) {
            const int token = t >> 2, part = t & 3, d0 = part * 16;
            short* yrow = ybuf + token * 72 + d0;
            if (token < N) {
                const int row = (token / P + L) * 9 + token % P + L;
                const float* xr = xs + row * 68 + d0;
                f32x4 v[4];
                #pragma unroll
                for (int k = 0; k < 4; ++k) v[k] = *(const f32x4*)(xr + 4 * k);
                float s1, s2;
                stats_tree<4>(v, s1, s2);
                s1 += __shfl_xor(s1, 1); s2 += __shfl_xor(s2, 1);
                s1 += __shfl_xor(s1, 2); s2 += __shfl_xor(s2, 2);
                const float m = s1 * 0.015625f;
                const float r = rsqrtf(s2 * 0.015625f - m * m + 1e-5f);
                uint4v w0, w1v;
                #pragma unroll
                for (int k = 0; k < 4; ++k) {
                    f32x4 g  = *(const f32x4*)&ln1_g[L * 64 + d0 + 4 * k];
                    f32x4 bb = *(const f32x4*)&ln1_b[L * 64 + d0 + 4 * k];
                    unsigned p0 = pk2((v[k][0]-m)*r*g[0]+bb[0], (v[k][1]-m)*r*g[1]+bb[1]);
                    unsigned p1 = pk2((v[k][2]-m)*r*g[2]+bb[2], (v[k][3]-m)*r*g[3]+bb[3]);
                    if (k == 0) { w0.x = p0; w0.y = p1; }
                    else if (k == 1) { w0.z = p0; w0.w = p1; }
                    else if (k == 2) { w1v.x = p0; w1v.y = p1; }
                    else { w1v.z = p0; w1v.w = p1; }
                }
                *(uint4v*)yrow = w0;
                *(uint4v*)(yrow + 8) = w1v;
            } else {
                uint4v z = {};
                *(uint4v*)yrow = z;
                *(uint4v*)(yrow + 8) = z;
            }
        }
        __syncthreads();
    }

    // ---- phase B: q GEMM only (swapped: lane=token, packed channel writes).
    //      Scale*log2e folded. k/v are computed in-register in phase C. ----
    {
        const short* wqL = ws + L * 12288;
        for (int u = wv; u < Mt * 4; u += 8) {
            const int mt = u >> 2, ct = u & 3;
            const short* yr = &ybuf[(16 * mt + lr) * 72 + lq * 8];
            short8v y0 = *(const short8v*)yr, y1 = *(const short8v*)(yr + 32);
            const short* wr = &wqL[(16 * ct + lr) * 64 + lq * 8];
            short8v w0 = *(const short8v*)wr, w1 = *(const short8v*)(wr + 32);
            f32x4 acc = mfma32(w0, y0, zero4);
            acc = mfma32(w1, y1, acc);
            f32x4 bq = *(const f32x4*)&b_qkv[L * 192 + 16 * ct + lq * 4];
            const int i = 16 * mt + lr;   // token
            unsigned p0 = pk2((acc[0]+bq[0])*SCL2E, (acc[1]+bq[1])*SCL2E);
            unsigned p1 = pk2((acc[2]+bq[2])*SCL2E, (acc[3]+bq[3])*SCL2E);
            unsigned* dst = (unsigned*)&qbf[i * 72 + 16 * ct + lq * 4];
            dst[0] = p0; dst[1] = p1;
        }
    }
    __syncthreads();

    // ---- phase C: fused k/v-GEMM + attention. wave = head h.
    //      k,v in registers (r13-verified fragments); q read from qbf (LDS)
    //      directly in the _1k B-fragment layout; attn-out overwrites qbf's
    //      own-head columns (disjoint across waves; rows read before write). ----
    {
        const int h = wv, a = h & 1, ct = h >> 1;
        const short* wqL = ws + L * 12288;

        // V pass: unswapped GEMM -> D fragment == PV A-operand fragment directly
        short4v vf[Mt];
        {
            const short* wvr = &wqL[(128 + 16 * ct + lr) * 64 + lq * 8];
            short8v wv0 = *(const short8v*)wvr, wv1 = *(const short8v*)(wvr + 32);
            const float vbi = b_qkv[L * 192 + 128 + 16 * ct + lr];
            #pragma unroll
            for (int mt = 0; mt < Mt; ++mt) {
                const short* yr = &ybuf[(16 * mt + lr) * 72 + lq * 8];
                short8v y0 = *(const short8v*)yr, y1 = *(const short8v*)(yr + 32);
                f32x4 acc = mfma32(y0, wv0, zero4);
                acc = mfma32(y1, wv1, acc);
                uint2v u;
                u.x = pk2(acc[0] + vbi, acc[1] + vbi);
                u.y = pk2(acc[2] + vbi, acc[3] + vbi);
                vf[mt] = __builtin_bit_cast(short4v, u);
            }
        }
        // K pass: swapped GEMM, redistribute (2 shfl) -> scores A fragment
        const int srcl = lr + 32 * a + (l & 16);
        uint2v kf[Mt];
        {
            const short* wkr = &wqL[(64 + 16 * ct + lr) * 64 + lq * 8];
            short8v wk0 = *(const short8v*)wkr, wk1 = *(const short8v*)(wkr + 32);
            f32x4 kb = *(const f32x4*)&b_qkv[L * 192 + 64 + 16 * ct + lq * 4];
            #pragma unroll
            for (int mt = 0; mt < Mt; ++mt) {
                const short* yr = &ybuf[(16 * mt + lr) * 72 + lq * 8];
                short8v y0 = *(const short8v*)yr, y1 = *(const short8v*)(yr + 32);
                f32x4 acc = mfma32(wk0, y0, zero4);
                acc = mfma32(wk1, y1, acc);
                unsigned ka = pk2(acc[0] + kb[0], acc[1] + kb[1]);
                unsigned kc = pk2(acc[2] + kb[2], acc[3] + kb[3]);
                unsigned u0 = (unsigned)__shfl((int)ka, srcl);
                unsigned u1 = (unsigned)__shfl((int)kc, srcl);
                uint2v kv; kv.x = (l < 32) ? u0 : 0u; kv.y = (l < 32) ? u1 : 0u;
                kf[mt] = kv;
            }
        }
        // scores + softmax + PV per query tile
        for (int mt = 0; mt < Mt; ++mt) {
            short4v qv = zero4s;
            if (l < 32)
                qv = *(const short4v*)&qbf[(16 * mt + lr) * 72 + 8 * h + 4 * ((l >> 4) & 1)];
            uint2v pkk[Mt];
            float psA = 0.f, psB = 0.f;
            #pragma unroll
            for (int jt = 0; jt < Mt; ++jt) {
                f32x4 s = mfma16(__builtin_bit_cast(short4v, kf[jt]), qv, zero4);
                float e0 = exp2fast(s[0]), e1 = exp2fast(s[1]);
                float e2 = exp2fast(s[2]), e3 = exp2fast(s[3]);
                if (jt == Mt - 1) {   // only the last tile contains pad keys
                    const int j0 = 16 * jt + lq * 4;
                    e0 = (j0 + 0 < N) ? e0 : 0.f;
                    e1 = (j0 + 1 < N) ? e1 : 0.f;
                    e2 = (j0 + 2 < N) ? e2 : 0.f;
                    e3 = (j0 + 3 < N) ? e3 : 0.f;
                }
                psA += e0 + e1; psB += e2 + e3;
                uint2v pv; pv.x = pk2(e0, e1); pv.y = pk2(e2, e3);
                pkk[jt] = pv;
            }
            float psum = psA + psB;
            float den = psum + __shfl_xor(psum, 16);
            den += __shfl_xor(den, 32);
            const float dinv = rcpfast(den);
            f32x4 po0 = zero4, po1 = zero4;
            #pragma unroll
            for (int jt = 0; jt < Mt; ++jt) {
                short4v bv = __builtin_bit_cast(short4v, pkk[jt]);
                if (jt & 1) po1 = mfma16(vf[jt], bv, po1);
                else        po0 = mfma16(vf[jt], bv, po0);
            }
            if ((lq >> 1) == a) {
                const int i = 16 * mt + lr;
                if (i < N) {
                    unsigned q0 = pk2((po0[0] + po1[0]) * dinv, (po0[1] + po1[1]) * dinv);
                    unsigned q1 = pk2((po0[2] + po1[2]) * dinv, (po0[3] + po1[3]) * dinv);
                    unsigned* dst = (unsigned*)&qbf[i * 72 + 8 * h + (lq & 1) * 4];
                    dst[0] = q0; dst[1] = q1;
                }
            }
        }
    }
    __syncthreads();

    // ---- phase D (fused, wave-local): w_o + residual + LN2 + MLP + residual
    //      + LN1-of-next-layer written into ybuf (dead after phase B). ----
    {
        if (wv < Mt) {
            const int mt = wv;
            const int i = 16 * mt + lr;          // token (this layer)
            const bool iok = (i < N);
            const int xrow = iok ? (i / P + L) * 9 + (i % P) + L : 0;
            float* xp = xs + xrow * 68;
            const short* yr = &qbf[i * 72 + lq * 8];   // attn-out
            short8v y0 = *(const short8v*)yr;
            short8v y1 = *(const short8v*)(yr + 32);
            const short* woL = ws + WS_WO + L * 4096;
            f32x4 xv[4];
            #pragma unroll
            for (int ctp = 0; ctp < 4; ++ctp) {
                const short* wr = &woL[(16 * ctp + lr) * 64 + lq * 8];
                f32x4 acc = mfma32(*(const short8v*)wr, y0, zero4);
                acc = mfma32(*(const short8v*)(wr + 32), y1, acc);
                f32x4 bo = *(const f32x4*)&b_o[L * 64 + 16 * ctp + 4 * lq];
                f32x4 xc = zero4;
                if (iok) xc = *(const f32x4*)(xp + 16 * ctp + 4 * lq);
                #pragma unroll
                for (int rg = 0; rg < 4; ++rg) xc[rg] += acc[rg] + bo[rg];
                xv[ctp] = xc;
            }
            float s1, s2;
            stats_tree<4>(xv, s1, s2);
            s1 += __shfl_xor(s1, 16); s2 += __shfl_xor(s2, 16);
            s1 += __shfl_xor(s1, 32); s2 += __shfl_xor(s2, 32);
            const float m = s1 * 0.015625f;
            const float r = rsqrtf(s2 * 0.015625f - m * m + 1e-5f);
            unsigned* abw = (unsigned*)&qbf[i * 72];
            #pragma unroll
            for (int ctp = 0; ctp < 4; ++ctp) {
                f32x4 g  = *(const f32x4*)&ln2_g[L * 64 + 16 * ctp + 4 * lq];
                f32x4 bb = *(const f32x4*)&ln2_b[L * 64 + 16 * ctp + 4 * lq];
                abw[8 * ctp + 2 * lq]     = pk2((xv[ctp][0]-m)*r*g[0]+bb[0],
                                                (xv[ctp][1]-m)*r*g[1]+bb[1]);
                abw[8 * ctp + 2 * lq + 1] = pk2((xv[ctp][2]-m)*r*g[2]+bb[2],
                                                (xv[ctp][3]-m)*r*g[3]+bb[3]);
            }
            // MLP up (same-wave LDS round-trip, matched unsigned types)
            uint4v ua0 = *(const uint4v*)(abw + 4 * lq);
            uint4v ua1 = *(const uint4v*)(abw + 16 + 4 * lq);
            const short* w1L = ws + WS_W1 + L * 1024;
            short8v a10 = __builtin_bit_cast(short8v, ua0);
            short8v a11 = __builtin_bit_cast(short8v, ua1);
            short8v b10 = *(const short8v*)&w1L[lr * 64 + lq * 8];
            short8v b11 = *(const short8v*)&w1L[lr * 64 + lq * 8 + 32];
            f32x4 hA = mfma32(a10, b10, zero4);
            hA = mfma32(a11, b11, hA);
            if (lr < 8) {
                const float bg = b1[L * 8 + lr];
                #pragma unroll
                for (int rg = 0; rg < 4; ++rg)
                    hb[(16 * mt + 4 * lq + rg) * 8 + lr] = bf1(gelu_f(hA[rg] + bg));
            }
            // MLP down, swapped orientation: D[ch 16ctp+4lq+rg][tok lr]
            short8v hbf = (lq == 0) ? *(const short8v*)&hb[(16 * mt + lr) * 8] : zero8;
            const short* w2L = ws + WS_W2 + L * 512;
            f32x4 xf[4];
            #pragma unroll
            for (int ctp = 0; ctp < 4; ++ctp) {
                short8v a2 = (lq == 0) ? *(const short8v*)&w2L[(16 * ctp + lr) * 8] : zero8;
                f32x4 dacc = mfma32(a2, hbf, zero4);
                f32x4 b2v = *(const f32x4*)&b2[L * 64 + 16 * ctp + 4 * lq];
                #pragma unroll
                for (int rg = 0; rg < 4; ++rg) xf[ctp][rg] = xv[ctp][rg] + dacc[rg] + b2v[rg];
                if (iok) *(f32x4*)(xp + 16 * ctp + 4 * lq) = xf[ctp];
            }
            if (!LAST) {
                // LN1 of the next layer, straight from registers -> ybuf
                float t1, t2;
                stats_tree<4>(xf, t1, t2);
                t1 += __shfl_xor(t1, 16); t2 += __shfl_xor(t2, 16);
                t1 += __shfl_xor(t1, 32); t2 += __shfl_xor(t2, 32);
                const float mn = t1 * 0.015625f;
                const float rn = rsqrtf(t2 * 0.015625f - mn * mn + 1e-5f);
                const int r_ = i / P, c_ = i % P;
                const bool vok = iok && r_ >= 1 && r_ <= P - 2 && c_ >= 1 && c_ <= P - 2;
                if (vok) {
                    const int j = (r_ - 1) * (P - 2) + (c_ - 1);
                    unsigned* yw = (unsigned*)&ybuf[j * 72];
                    #pragma unroll
                    for (int ctp = 0; ctp < 4; ++ctp) {
                        f32x4 g  = *(const f32x4*)&ln1_g[(L + 1) * 64 + 16 * ctp + 4 * lq];
                        f32x4 bb = *(const f32x4*)&ln1_b[(L + 1) * 64 + 16 * ctp + 4 * lq];
                        yw[8 * ctp + 2 * lq]     = pk2((xf[ctp][0]-mn)*rn*g[0]+bb[0],
                                                       (xf[ctp][1]-mn)*rn*g[1]+bb[1]);
                        yw[8 * ctp + 2 * lq + 1] = pk2((xf[ctp][2]-mn)*rn*g[2]+bb[2],
                                                       (xf[ctp][3]-mn)*rn*g[3]+bb[3]);
                    }
                }
            }
        } else if (!LAST && wv == Mt) {
            // zero next layer's pad rows [Nn, 16*Mtn) in ybuf
            constexpr int Pn = P - 2, Nn = Pn * Pn, Mtn = (Nn + 15) / 16;
            constexpr int PadU = (16 * Mtn - Nn) * 36;
            unsigned* zb = (unsigned*)(ybuf + Nn * 72);
            for (int z = l; z < PadU; z += 64) zb[z] = 0;
        }
    }
    __syncthreads();

    if (LAST) {
        for (int idx = t; idx < 576; idx += NT) {
            const int d = idx / 9, rc = idx % 9;
            const int row = (rc / 3 + 3) * 9 + rc % 3 + 3;
            out[(size_t)b * 576 + idx] = xs[row * 68 + d];
        }
    }
}

__global__ __launch_bounds__(NT, 6) void vit_kernel(
    const float* __restrict__ x_in, const short* __restrict__ ws,
    const float* __restrict__ b_qkv, const float* __restrict__ b_o,
    const float* __restrict__ ln1_g, const float* __restrict__ ln1_b,
    const float* __restrict__ ln2_g, const float* __restrict__ ln2_b,
    const float* __restrict__ b1,    const float* __restrict__ b2,
    float* __restrict__ out)
{
    __shared__ __align__(16) float xs[81 * 68];     // 22032 B
    __shared__ __align__(16) short ybuf[96 * 72];   // 13824 B  (LN1 in)
    __shared__ __align__(16) short qbf[96 * 72];    // 13824 B  (q, then attn-out)
    __shared__ __align__(16) short hb[96 * 8];      //  1536 B  (MLP hidden)

    const int b = blockIdx.x;
    const int t = threadIdx.x;

    const float* xin = x_in + (size_t)b * 5184;
    for (int q4 = t; q4 < 1296; q4 += NT) {
        const int i = q4 >> 4, dq = q4 & 15;
        *(f32x4*)&xs[i * 68 + dq * 4] = *(const f32x4*)&xin[i * 64 + dq * 4];
    }
    __syncthreads();

    layer_fn<81, 9, 0, true,  false>(xs, ybuf, qbf, hb, ws, b_qkv, b_o,
                                     ln1_g, ln1_b, ln2_g, ln2_b, b1, b2, out, b, t);
    layer_fn<49, 7, 1, false, false>(xs, ybuf, qbf, hb, ws, b_qkv, b_o,
                                     ln1_g, ln1_b, ln2_g, ln2_b, b1, b2, out, b, t);
    layer_fn<25, 5, 2, false, false>(xs, ybuf, qbf, hb, ws, b_qkv, b_o,
                                     ln1_g, ln1_b, ln2_g, ln2_b, b1, b2, out, b, t);
    layer_fn<9,  3, 3, false, true >(xs, ybuf, qbf, hb, ws, b_qkv, b_o,
                                     ln1_g, ln1_b, ln2_g, ln2_b, b1, b2, out, b, t);
}

extern "C" void kernel_launch(void* const* d_in, const int* in_sizes, int n_in,
                              void* d_out, int out_size, void* d_ws, size_t ws_size,
                              hipStream_t stream) {
    (void)n_in; (void)out_size; (void)ws_size;
    const float* x     = (const float*)d_in[0];
    const float* w_qkv = (const float*)d_in[1];
    const float* b_qkv = (const float*)d_in[2];
    const float* w_o   = (const float*)d_in[3];
    const float* b_o   = (const float*)d_in[4];
    const float* ln1_g = (const float*)d_in[5];
    const float* ln1_b = (const float*)d_in[6];
    const float* ln2_g = (const float*)d_in[7];
    const float* ln2_b = (const float*)d_in[8];
    const float* w1    = (const float*)d_in[9];
    const float* b1    = (const float*)d_in[10];
    const float* w2    = (const float*)d_in[11];
    const float* b2    = (const float*)d_in[12];
    short* ws = (short*)d_ws;

    prep_kernel<<<dim3((WS_TOT + 255) / 256), dim3(256), 0, stream>>>(w_qkv, w_o, w1, w2, ws);

    int B = in_sizes[0] / (81 * 64);
    vit_kernel<<<dim3(B), dim3(NT), 0, stream>>>(
        x, ws, b_qkv, b_o, ln1_g, ln1_b, ln2_g, ln2_b, b1, b2, (float*)d_out);
}

// Round 16
// 336.655 us; speedup vs baseline: 1.3823x; 1.0041x over previous
//
#include <hip/hip_runtime.h>
#include <hip/hip_bf16.h>
#include <math.h>

#define NT 512

typedef __attribute__((ext_vector_type(8))) short short8v;
typedef __attribute__((ext_vector_type(4))) short short4v;
typedef __attribute__((ext_vector_type(4))) float f32x4;
typedef __attribute__((ext_vector_type(2))) unsigned uint2v;
typedef __attribute__((ext_vector_type(4))) unsigned uint4v;

__device__ __forceinline__ unsigned short f2bf(float x) {   // prep kernel only
    unsigned u = __float_as_uint(x);
    unsigned r = ((u >> 16) & 1u) + 0x7FFFu;
    return (unsigned short)((u + r) >> 16);
}
__device__ __forceinline__ unsigned pk2(float a, float b) {
    __hip_bfloat162 h = __float22bfloat162_rn(make_float2(a, b));
    unsigned r;
    __builtin_memcpy(&r, &h, sizeof(r));
    return r;
}
__device__ __forceinline__ short bf1(float a) {
    __hip_bfloat16 h = __float2bfloat16(a);
    short r;
    __builtin_memcpy(&r, &h, sizeof(r));
    return r;
}
__device__ __forceinline__ float exp2fast(float x) {
#if __has_builtin(__builtin_amdgcn_exp2f)
    return __builtin_amdgcn_exp2f(x);
#else
    return exp2f(x);
#endif
}
__device__ __forceinline__ float rcpfast(float x) {
#if __has_builtin(__builtin_amdgcn_rcpf)
    return __builtin_amdgcn_rcpf(x);
#else
    return 1.0f / x;
#endif
}
// tanh-form gelu via exp2 + rcp (|err| vs erf-gelu ~3e-3, inside tolerance)
__device__ __forceinline__ float gelu_f(float x) {
    float x3 = x * x * x;
    float e = exp2fast(-2.3022079f * x - 0.1029432f * x3);
    return x * rcpfast(1.0f + e);
}
__device__ __forceinline__ f32x4 mfma32(short8v a, short8v b, f32x4 c) {
    return __builtin_amdgcn_mfma_f32_16x16x32_bf16(a, b, c, 0, 0, 0);
}
__device__ __forceinline__ f32x4 mfma16(short4v a, short4v b, f32x4 c) {
    return __builtin_amdgcn_mfma_f32_16x16x16bf16_1k(a, b, c, 0, 0, 0);
}

template<int M>
__device__ __forceinline__ void stats_tree(const f32x4* v, float& s1o, float& s2o) {
    float a[M], b[M];
    #pragma unroll
    for (int i = 0; i < M; ++i) {
        a[i] = (v[i][0] + v[i][1]) + (v[i][2] + v[i][3]);
        float q0 = v[i][0] * v[i][0], q1 = v[i][1] * v[i][1];
        float q2 = v[i][2] * v[i][2], q3 = v[i][3] * v[i][3];
        b[i] = (q0 + q1) + (q2 + q3);
    }
    #pragma unroll
    for (int s = 1; s < M; s *= 2)
        #pragma unroll
        for (int i = 0; i + s < M; i += 2 * s) { a[i] += a[i + s]; b[i] += b[i + s]; }
    s1o = a[0]; s2o = b[0];
}

// ws layout (bf16 shorts): wqkvT[L][192][64] @0 ; woT[L][64][64] @49152 ;
//                          w1T[L][16][64] @65536 (rows j>=8 zero) ; w2T[L][64][8] @69632
#define WS_WO 49152
#define WS_W1 65536
#define WS_W2 69632
#define WS_TOT 71680

__global__ __launch_bounds__(256) void prep_kernel(
    const float* __restrict__ w_qkv, const float* __restrict__ w_o,
    const float* __restrict__ w1, const float* __restrict__ w2,
    short* __restrict__ ws)
{
    int idx = blockIdx.x * 256 + threadIdx.x;
    if (idx < WS_WO) {
        int l = idx / 12288, r = idx % 12288, c = r >> 6, d = r & 63;
        ws[idx] = (short)f2bf(w_qkv[l * 12288 + d * 192 + c]);
    } else if (idx < WS_W1) {
        int k = idx - WS_WO; int l = k / 4096, r = k % 4096, c = r >> 6, d = r & 63;
        ws[idx] = (short)f2bf(w_o[l * 4096 + d * 64 + c]);
    } else if (idx < WS_W2) {
        int k = idx - WS_W1; int l = k / 1024, r = k % 1024, j = r >> 6, d = r & 63;
        ws[idx] = (j < 8) ? (short)f2bf(w1[l * 512 + d * 8 + j]) : (short)0;
    } else if (idx < WS_TOT) {
        int k = idx - WS_W2; int l = k / 512, r = k % 512, c = r >> 3, j = r & 7;
        ws[idx] = (short)f2bf(w2[l * 512 + j * 64 + c]);
    }
}

// LDS (51.2 KB -> 3 blocks/CU): xs fp32 [81][68] (full 9x9 grid, ring-indexed);
// ybuf bf16 [96][72] = LN1 input; qbf bf16 [96][72] = q (phase B) then attn-out
// (phase C overwrites per-head columns after use); hb bf16 [96][8] MLP hidden.
// k and v live in registers (per-wave GEMM, 2x duplicated across head pairs).
template<int N, int P, int L, bool FIRST, bool LAST>
__device__ __forceinline__ void layer_fn(
    float* __restrict__ xs, short* __restrict__ ybuf, short* __restrict__ qbf,
    short* __restrict__ hb, const short* __restrict__ ws,
    const float* __restrict__ b_qkv, const float* __restrict__ b_o,
    const float* __restrict__ ln1_g, const float* __restrict__ ln1_b,
    const float* __restrict__ ln2_g, const float* __restrict__ ln2_b,
    const float* __restrict__ b1,    const float* __restrict__ b2,
    float* __restrict__ out, int b, int t)
{
    constexpr int Mt = (N + 15) / 16;
    constexpr float SCL2E = 0.51010905835f;   // (HEAD_DIM/HEADS)^-0.5 * log2(e)
    const int wv = t >> 6, l = t & 63, lr = l & 15, lq = l >> 4;
    short8v zero8 = {};
    short4v zero4s = {};
    f32x4 zero4 = {0.f, 0.f, 0.f, 0.f};

    // ---- phase A (first layer only): LN1 -> ybuf. 4 lanes per token ----
    if (FIRST) {
        if (t < 64 * Mt) {
            const int token = t >> 2, part = t & 3, d0 = part * 16;
            short* yrow = ybuf + token * 72 + d0;
            if (token < N) {
                const int row = (token / P + L) * 9 + token % P + L;
                const float* xr = xs + row * 68 + d0;
                f32x4 v[4];
                #pragma unroll
                for (int k = 0; k < 4; ++k) v[k] = *(const f32x4*)(xr + 4 * k);
                float s1, s2;
                stats_tree<4>(v, s1, s2);
                s1 += __shfl_xor(s1, 1); s2 += __shfl_xor(s2, 1);
                s1 += __shfl_xor(s1, 2); s2 += __shfl_xor(s2, 2);
                const float m = s1 * 0.015625f;
                const float r = rsqrtf(s2 * 0.015625f - m * m + 1e-5f);
                uint4v w0, w1v;
                #pragma unroll
                for (int k = 0; k < 4; ++k) {
                    f32x4 g  = *(const f32x4*)&ln1_g[L * 64 + d0 + 4 * k];
                    f32x4 bb = *(const f32x4*)&ln1_b[L * 64 + d0 + 4 * k];
                    unsigned p0 = pk2((v[k][0]-m)*r*g[0]+bb[0], (v[k][1]-m)*r*g[1]+bb[1]);
                    unsigned p1 = pk2((v[k][2]-m)*r*g[2]+bb[2], (v[k][3]-m)*r*g[3]+bb[3]);
                    if (k == 0) { w0.x = p0; w0.y = p1; }
                    else if (k == 1) { w0.z = p0; w0.w = p1; }
                    else if (k == 2) { w1v.x = p0; w1v.y = p1; }
                    else { w1v.z = p0; w1v.w = p1; }
                }
                *(uint4v*)yrow = w0;
                *(uint4v*)(yrow + 8) = w1v;
            } else {
                uint4v z = {};
                *(uint4v*)yrow = z;
                *(uint4v*)(yrow + 8) = z;
            }
        }
        __syncthreads();
    }

    // ---- phase B: q GEMM only (swapped: lane=token, packed channel writes).
    //      Scale*log2e folded. k/v are computed in-register in phase C. ----
    {
        const short* wqL = ws + L * 12288;
        for (int u = wv; u < Mt * 4; u += 8) {
            const int mt = u >> 2, ct = u & 3;
            const short* yr = &ybuf[(16 * mt + lr) * 72 + lq * 8];
            short8v y0 = *(const short8v*)yr, y1 = *(const short8v*)(yr + 32);
            const short* wr = &wqL[(16 * ct + lr) * 64 + lq * 8];
            short8v w0 = *(const short8v*)wr, w1 = *(const short8v*)(wr + 32);
            f32x4 acc = mfma32(w0, y0, zero4);
            acc = mfma32(w1, y1, acc);
            f32x4 bq = *(const f32x4*)&b_qkv[L * 192 + 16 * ct + lq * 4];
            const int i = 16 * mt + lr;   // token
            unsigned p0 = pk2((acc[0]+bq[0])*SCL2E, (acc[1]+bq[1])*SCL2E);
            unsigned p1 = pk2((acc[2]+bq[2])*SCL2E, (acc[3]+bq[3])*SCL2E);
            unsigned* dst = (unsigned*)&qbf[i * 72 + 16 * ct + lq * 4];
            dst[0] = p0; dst[1] = p1;
        }
    }
    __syncthreads();

    // ---- phase C: fused k/v-GEMM + attention. wave = head h.
    //      k,v in registers; q read from qbf directly in _1k B-fragment layout;
    //      PV fused into the scores loop (no pkk array -> minimal live set);
    //      attn-out overwrites qbf's own-head columns. ----
    {
        const int h = wv, a = h & 1, ct = h >> 1;
        const short* wqL = ws + L * 12288;

        // V pass: unswapped GEMM -> D fragment == PV A-operand fragment directly
        short4v vf[Mt];
        {
            const short* wvr = &wqL[(128 + 16 * ct + lr) * 64 + lq * 8];
            short8v wv0 = *(const short8v*)wvr, wv1 = *(const short8v*)(wvr + 32);
            const float vbi = b_qkv[L * 192 + 128 + 16 * ct + lr];
            #pragma unroll
            for (int mt = 0; mt < Mt; ++mt) {
                const short* yr = &ybuf[(16 * mt + lr) * 72 + lq * 8];
                short8v y0 = *(const short8v*)yr, y1 = *(const short8v*)(yr + 32);
                f32x4 acc = mfma32(y0, wv0, zero4);
                acc = mfma32(y1, wv1, acc);
                uint2v u;
                u.x = pk2(acc[0] + vbi, acc[1] + vbi);
                u.y = pk2(acc[2] + vbi, acc[3] + vbi);
                vf[mt] = __builtin_bit_cast(short4v, u);
            }
        }
        // K pass: swapped GEMM, redistribute (2 shfl) -> scores A fragment
        const int srcl = lr + 32 * a + (l & 16);
        uint2v kf[Mt];
        {
            const short* wkr = &wqL[(64 + 16 * ct + lr) * 64 + lq * 8];
            short8v wk0 = *(const short8v*)wkr, wk1 = *(const short8v*)(wkr + 32);
            f32x4 kb = *(const f32x4*)&b_qkv[L * 192 + 64 + 16 * ct + lq * 4];
            #pragma unroll
            for (int mt = 0; mt < Mt; ++mt) {
                const short* yr = &ybuf[(16 * mt + lr) * 72 + lq * 8];
                short8v y0 = *(const short8v*)yr, y1 = *(const short8v*)(yr + 32);
                f32x4 acc = mfma32(wk0, y0, zero4);
                acc = mfma32(wk1, y1, acc);
                unsigned ka = pk2(acc[0] + kb[0], acc[1] + kb[1]);
                unsigned kc = pk2(acc[2] + kb[2], acc[3] + kb[3]);
                unsigned u0 = (unsigned)__shfl((int)ka, srcl);
                unsigned u1 = (unsigned)__shfl((int)kc, srcl);
                uint2v kv; kv.x = (l < 32) ? u0 : 0u; kv.y = (l < 32) ? u1 : 0u;
                kf[mt] = kv;
            }
        }
        // scores + softmax + PV per query tile (PV fused per-jt; no P array)
        for (int mt = 0; mt < Mt; ++mt) {
            short4v qv = zero4s;
            if (l < 32)
                qv = *(const short4v*)&qbf[(16 * mt + lr) * 72 + 8 * h + 4 * ((l >> 4) & 1)];
            float psA = 0.f, psB = 0.f;
            f32x4 po0 = zero4, po1 = zero4;
            #pragma unroll
            for (int jt = 0; jt < Mt; ++jt) {
                f32x4 s = mfma16(__builtin_bit_cast(short4v, kf[jt]), qv, zero4);
                float e0 = exp2fast(s[0]), e1 = exp2fast(s[1]);
                float e2 = exp2fast(s[2]), e3 = exp2fast(s[3]);
                if (jt == Mt - 1) {   // only the last tile contains pad keys
                    const int j0 = 16 * jt + lq * 4;
                    e0 = (j0 + 0 < N) ? e0 : 0.f;
                    e1 = (j0 + 1 < N) ? e1 : 0.f;
                    e2 = (j0 + 2 < N) ? e2 : 0.f;
                    e3 = (j0 + 3 < N) ? e3 : 0.f;
                }
                psA += e0 + e1; psB += e2 + e3;
                uint2v pv; pv.x = pk2(e0, e1); pv.y = pk2(e2, e3);
                short4v bv = __builtin_bit_cast(short4v, pv);
                if (jt & 1) po1 = mfma16(vf[jt], bv, po1);
                else        po0 = mfma16(vf[jt], bv, po0);
            }
            float psum = psA + psB;
            float den = psum + __shfl_xor(psum, 16);
            den += __shfl_xor(den, 32);
            const float dinv = rcpfast(den);
            if ((lq >> 1) == a) {
                const int i = 16 * mt + lr;
                if (i < N) {
                    unsigned q0 = pk2((po0[0] + po1[0]) * dinv, (po0[1] + po1[1]) * dinv);
                    unsigned q1 = pk2((po0[2] + po1[2]) * dinv, (po0[3] + po1[3]) * dinv);
                    unsigned* dst = (unsigned*)&qbf[i * 72 + 8 * h + (lq & 1) * 4];
                    dst[0] = q0; dst[1] = q1;
                }
            }
        }
    }
    __syncthreads();

    // ---- phase D (fused, wave-local): w_o + residual + LN2 + MLP + residual
    //      + LN1-of-next-layer written into ybuf (dead after phase B). ----
    {
        if (wv < Mt) {
            const int mt = wv;
            const int i = 16 * mt + lr;          // token (this layer)
            const bool iok = (i < N);
            const int xrow = iok ? (i / P + L) * 9 + (i % P) + L : 0;
            float* xp = xs + xrow * 68;
            const short* yr = &qbf[i * 72 + lq * 8];   // attn-out
            short8v y0 = *(const short8v*)yr;
            short8v y1 = *(const short8v*)(yr + 32);
            const short* woL = ws + WS_WO + L * 4096;
            f32x4 xv[4];
            #pragma unroll
            for (int ctp = 0; ctp < 4; ++ctp) {
                const short* wr = &woL[(16 * ctp + lr) * 64 + lq * 8];
                f32x4 acc = mfma32(*(const short8v*)wr, y0, zero4);
                acc = mfma32(*(const short8v*)(wr + 32), y1, acc);
                f32x4 bo = *(const f32x4*)&b_o[L * 64 + 16 * ctp + 4 * lq];
                f32x4 xc = zero4;
                if (iok) xc = *(const f32x4*)(xp + 16 * ctp + 4 * lq);
                #pragma unroll
                for (int rg = 0; rg < 4; ++rg) xc[rg] += acc[rg] + bo[rg];
                xv[ctp] = xc;
            }
            float s1, s2;
            stats_tree<4>(xv, s1, s2);
            s1 += __shfl_xor(s1, 16); s2 += __shfl_xor(s2, 16);
            s1 += __shfl_xor(s1, 32); s2 += __shfl_xor(s2, 32);
            const float m = s1 * 0.015625f;
            const float r = rsqrtf(s2 * 0.015625f - m * m + 1e-5f);
            unsigned* abw = (unsigned*)&qbf[i * 72];
            #pragma unroll
            for (int ctp = 0; ctp < 4; ++ctp) {
                f32x4 g  = *(const f32x4*)&ln2_g[L * 64 + 16 * ctp + 4 * lq];
                f32x4 bb = *(const f32x4*)&ln2_b[L * 64 + 16 * ctp + 4 * lq];
                abw[8 * ctp + 2 * lq]     = pk2((xv[ctp][0]-m)*r*g[0]+bb[0],
                                                (xv[ctp][1]-m)*r*g[1]+bb[1]);
                abw[8 * ctp + 2 * lq + 1] = pk2((xv[ctp][2]-m)*r*g[2]+bb[2],
                                                (xv[ctp][3]-m)*r*g[3]+bb[3]);
            }
            // MLP up (same-wave LDS round-trip, matched unsigned types)
            uint4v ua0 = *(const uint4v*)(abw + 4 * lq);
            uint4v ua1 = *(const uint4v*)(abw + 16 + 4 * lq);
            const short* w1L = ws + WS_W1 + L * 1024;
            short8v a10 = __builtin_bit_cast(short8v, ua0);
            short8v a11 = __builtin_bit_cast(short8v, ua1);
            short8v b10 = *(const short8v*)&w1L[lr * 64 + lq * 8];
            short8v b11 = *(const short8v*)&w1L[lr * 64 + lq * 8 + 32];
            f32x4 hA = mfma32(a10, b10, zero4);
            hA = mfma32(a11, b11, hA);
            if (lr < 8) {
                const float bg = b1[L * 8 + lr];
                #pragma unroll
                for (int rg = 0; rg < 4; ++rg)
                    hb[(16 * mt + 4 * lq + rg) * 8 + lr] = bf1(gelu_f(hA[rg] + bg));
            }
            // MLP down, swapped orientation: D[ch 16ctp+4lq+rg][tok lr]
            short8v hbf = (lq == 0) ? *(const short8v*)&hb[(16 * mt + lr) * 8] : zero8;
            const short* w2L = ws + WS_W2 + L * 512;
            f32x4 xf[4];
            #pragma unroll
            for (int ctp = 0; ctp < 4; ++ctp) {
                short8v a2 = (lq == 0) ? *(const short8v*)&w2L[(16 * ctp + lr) * 8] : zero8;
                f32x4 dacc = mfma32(a2, hbf, zero4);
                f32x4 b2v = *(const f32x4*)&b2[L * 64 + 16 * ctp + 4 * lq];
                #pragma unroll
                for (int rg = 0; rg < 4; ++rg) xf[ctp][rg] = xv[ctp][rg] + dacc[rg] + b2v[rg];
                if (iok) *(f32x4*)(xp + 16 * ctp + 4 * lq) = xf[ctp];
            }
            if (!LAST) {
                // LN1 of the next layer, straight from registers -> ybuf
                float t1, t2;
                stats_tree<4>(xf, t1, t2);
                t1 += __shfl_xor(t1, 16); t2 += __shfl_xor(t2, 16);
                t1 += __shfl_xor(t1, 32); t2 += __shfl_xor(t2, 32);
                const float mn = t1 * 0.015625f;
                const float rn = rsqrtf(t2 * 0.015625f - mn * mn + 1e-5f);
                const int r_ = i / P, c_ = i % P;
                const bool vok = iok && r_ >= 1 && r_ <= P - 2 && c_ >= 1 && c_ <= P - 2;
                if (vok) {
                    const int j = (r_ - 1) * (P - 2) + (c_ - 1);
                    unsigned* yw = (unsigned*)&ybuf[j * 72];
                    #pragma unroll
                    for (int ctp = 0; ctp < 4; ++ctp) {
                        f32x4 g  = *(const f32x4*)&ln1_g[(L + 1) * 64 + 16 * ctp + 4 * lq];
                        f32x4 bb = *(const f32x4*)&ln1_b[(L + 1) * 64 + 16 * ctp + 4 * lq];
                        yw[8 * ctp + 2 * lq]     = pk2((xf[ctp][0]-mn)*rn*g[0]+bb[0],
                                                       (xf[ctp][1]-mn)*rn*g[1]+bb[1]);
                        yw[8 * ctp + 2 * lq + 1] = pk2((xf[ctp][2]-mn)*rn*g[2]+bb[2],
                                                       (xf[ctp][3]-mn)*rn*g[3]+bb[3]);
                    }
                }
            }
        } else if (!LAST && wv == Mt) {
            // zero next layer's pad rows [Nn, 16*Mtn) in ybuf
            constexpr int Pn = P - 2, Nn = Pn * Pn, Mtn = (Nn + 15) / 16;
            constexpr int PadU = (16 * Mtn - Nn) * 36;
            unsigned* zb = (unsigned*)(ybuf + Nn * 72);
            for (int z = l; z < PadU; z += 64) zb[z] = 0;
        }
    }
    __syncthreads();

    if (LAST) {
        for (int idx = t; idx < 576; idx += NT) {
            const int d = idx / 9, rc = idx % 9;
            const int row = (rc / 3 + 3) * 9 + rc % 3 + 3;
            out[(size_t)b * 576 + idx] = xs[row * 68 + d];
        }
    }
}

__global__ __launch_bounds__(NT, 6) void vit_kernel(
    const float* __restrict__ x_in, const short* __restrict__ ws,
    const float* __restrict__ b_qkv, const float* __restrict__ b_o,
    const float* __restrict__ ln1_g, const float* __restrict__ ln1_b,
    const float* __restrict__ ln2_g, const float* __restrict__ ln2_b,
    const float* __restrict__ b1,    const float* __restrict__ b2,
    float* __restrict__ out)
{
    __shared__ __align__(16) float xs[81 * 68];     // 22032 B
    __shared__ __align__(16) short ybuf[96 * 72];   // 13824 B  (LN1 in)
    __shared__ __align__(16) short qbf[96 * 72];    // 13824 B  (q, then attn-out)
    __shared__ __align__(16) short hb[96 * 8];      //  1536 B  (MLP hidden)

    const int b = blockIdx.x;
    const int t = threadIdx.x;

    const float* xin = x_in + (size_t)b * 5184;
    for (int q4 = t; q4 < 1296; q4 += NT) {
        const int i = q4 >> 4, dq = q4 & 15;
        *(f32x4*)&xs[i * 68 + dq * 4] = *(const f32x4*)&xin[i * 64 + dq * 4];
    }
    __syncthreads();

    layer_fn<81, 9, 0, true,  false>(xs, ybuf, qbf, hb, ws, b_qkv, b_o,
                                     ln1_g, ln1_b, ln2_g, ln2_b, b1, b2, out, b, t);
    layer_fn<49, 7, 1, false, false>(xs, ybuf, qbf, hb, ws, b_qkv, b_o,
                                     ln1_g, ln1_b, ln2_g, ln2_b, b1, b2, out, b, t);
    layer_fn<25, 5, 2, false, false>(xs, ybuf, qbf, hb, ws, b_qkv, b_o,
                                     ln1_g, ln1_b, ln2_g, ln2_b, b1, b2, out, b, t);
    layer_fn<9,  3, 3, false, true >(xs, ybuf, qbf, hb, ws, b_qkv, b_o,
                                     ln1_g, ln1_b, ln2_g, ln2_b, b1, b2, out, b, t);
}

extern "C" void kernel_launch(void* const* d_in, const int* in_sizes, int n_in,
                              void* d_out, int out_size, void* d_ws, size_t ws_size,
                              hipStream_t stream) {
    (void)n_in; (void)out_size; (void)ws_size;
    const float* x     = (const float*)d_in[0];
    const float* w_qkv = (const float*)d_in[1];
    const float* b_qkv = (const float*)d_in[2];
    const float* w_o   = (const float*)d_in[3];
    const float* b_o   = (const float*)d_in[4];
    const float* ln1_g = (const float*)d_in[5];
    const float* ln1_b = (const float*)d_in[6];
    const float* ln2_g = (const float*)d_in[7];
    const float* ln2_b = (const float*)d_in[8];
    const float* w1    = (const float*)d_in[9];
    const float* b1    = (const float*)d_in[10];
    const float* w2    = (const float*)d_in[11];
    const float* b2    = (const float*)d_in[12];
    short* ws = (short*)d_ws;

    prep_kernel<<<dim3((WS_TOT + 255) / 256), dim3(256), 0, stream>>>(w_qkv, w_o, w1, w2, ws);

    int B = in_sizes[0] / (81 * 64);
    vit_kernel<<<dim3(B), dim3(NT), 0, stream>>>(
        x, ws, b_qkv, b_o, ln1_g, ln1_b, ln2_g, ln2_b, b1, b2, (float*)d_out);
}